// Round 1
// baseline (1795.466 us; speedup 1.0000x reference)
//
#include <hip/hip_runtime.h>
#include <math.h>

// Problem constants
#define Bsz   4
#define Tsz   4096
#define Csz   1024
#define Hn    16
#define DHn   64
#define NTOT  (Bsz * Tsz)      // 16384 rows of x
#define M3    (3 * Csz)        // 3072
#define Fn    2049             // T/2 + 1
#define BHn   (Bsz * Hn)       // 64

// ---------------------------------------------------------------------------
// GEMM1: qkvT[m][n] = sum_k W_qkv[m][k] * x[n][k]
// A = W_qkv [3072][1024] row-major (K-contig), B = x [16384][1024] row-major
// (K-contig). Classic 128x128 tile, K-step 16, 256 threads, 8x8 per thread.
// ---------------------------------------------------------------------------
__global__ __launch_bounds__(256)
void gemm1_kernel(const float* __restrict__ A, const float* __restrict__ B,
                  float* __restrict__ C) {
  __shared__ float As[16][132];   // [k][m]
  __shared__ float Bs[16][132];   // [k][n]
  const int tid = threadIdx.x;
  const int tx = tid & 15, ty = tid >> 4;
  const int m0 = blockIdx.y * 128, n0 = blockIdx.x * 128;
  const int lr = tid >> 1;            // 0..127
  const int lc = (tid & 1) << 3;      // 0 or 8

  float acc[8][8];
#pragma unroll
  for (int i = 0; i < 8; ++i)
#pragma unroll
    for (int j = 0; j < 8; ++j) acc[i][j] = 0.f;

  const float* Ap = A + (size_t)(m0 + lr) * Csz + lc;
  const float* Bp = B + (size_t)(n0 + lr) * Csz + lc;

  for (int k0 = 0; k0 < Csz; k0 += 16) {
    float4 a0 = *(const float4*)(Ap + k0);
    float4 a1 = *(const float4*)(Ap + k0 + 4);
    float4 b0 = *(const float4*)(Bp + k0);
    float4 b1 = *(const float4*)(Bp + k0 + 4);
    __syncthreads();
    As[lc + 0][lr] = a0.x; As[lc + 1][lr] = a0.y; As[lc + 2][lr] = a0.z; As[lc + 3][lr] = a0.w;
    As[lc + 4][lr] = a1.x; As[lc + 5][lr] = a1.y; As[lc + 6][lr] = a1.z; As[lc + 7][lr] = a1.w;
    Bs[lc + 0][lr] = b0.x; Bs[lc + 1][lr] = b0.y; Bs[lc + 2][lr] = b0.z; Bs[lc + 3][lr] = b0.w;
    Bs[lc + 4][lr] = b1.x; Bs[lc + 5][lr] = b1.y; Bs[lc + 6][lr] = b1.z; Bs[lc + 7][lr] = b1.w;
    __syncthreads();
#pragma unroll
    for (int kk = 0; kk < 16; ++kk) {
      float a[8], b[8];
      *(float4*)&a[0] = *(const float4*)&As[kk][ty * 8];
      *(float4*)&a[4] = *(const float4*)&As[kk][ty * 8 + 4];
      *(float4*)&b[0] = *(const float4*)&Bs[kk][tx * 8];
      *(float4*)&b[4] = *(const float4*)&Bs[kk][tx * 8 + 4];
#pragma unroll
      for (int i = 0; i < 8; ++i)
#pragma unroll
        for (int j = 0; j < 8; ++j) acc[i][j] = fmaf(a[i], b[j], acc[i][j]);
    }
  }
#pragma unroll
  for (int i = 0; i < 8; ++i) {
    float* cp = C + (size_t)(m0 + ty * 8 + i) * NTOT + n0 + tx * 8;
    *(float4*)cp       = make_float4(acc[i][0], acc[i][1], acc[i][2], acc[i][3]);
    *(float4*)(cp + 4) = make_float4(acc[i][4], acc[i][5], acc[i][6], acc[i][7]);
  }
}

// ---------------------------------------------------------------------------
// 4096-point complex Stockham FFT in LDS (radix-2, 12 stages, autosort).
// Result ends in X (even number of buffer swaps). sign=-1 forward, +1 inverse
// (inverse is unnormalized; caller scales by 1/4096).
// ---------------------------------------------------------------------------
__device__ __forceinline__ void fft4096(float2* X, float2* Y, int tid, float sign) {
  float2* src = X;
  float2* dst = Y;
#pragma unroll 1
  for (int stage = 0; stage < 12; ++stage) {
    const int s = 1 << stage;
    __syncthreads();
#pragma unroll
    for (int it = 0; it < 8; ++it) {
      const int idx = tid + (it << 8);          // < 2048
      const int sp = idx & ~(s - 1);            // s * p
      float2 a = src[idx];
      float2 b = src[idx + 2048];
      float ang = sign * (6.28318530717958647692f / 4096.0f) * (float)sp;
      float sn, cs;
      __sincosf(ang, &sn, &cs);
      float2 sum = make_float2(a.x + b.x, a.y + b.y);
      float2 dif = make_float2(a.x - b.x, a.y - b.y);
      float2 tw  = make_float2(dif.x * cs - dif.y * sn, dif.x * sn + dif.y * cs);
      const int o = idx + sp;
      dst[o] = sum;
      dst[o + s] = tw;
    }
    float2* t = src; src = dst; dst = t;
    s; // (no-op)
  }
  __syncthreads();
}

// ---------------------------------------------------------------------------
// qk_cross: one block per (b,h,d). Pack z = q + i*k, FFT, extract
// Re(conj(Q[f]) * K[f]) = 0.25 * Im(conj(Zf+Zc) * (Zf-Zc)), Zc = conj(Z[N-f]).
// Accumulate over d into attn_raw[b*H+h][f] via atomicAdd. Includes scale 1/8.
// ---------------------------------------------------------------------------
__global__ __launch_bounds__(256)
void qk_cross_kernel(const float* __restrict__ qkvT, float* __restrict__ attn_raw) {
  __shared__ float2 bufA[4096];
  __shared__ float2 bufB[4096];
  const int tid = threadIdx.x;
  const int blk = blockIdx.x;          // (b*16+h)*64 + d
  const int d = blk & 63;
  const int bh = blk >> 6;
  const int h = bh & 15;
  const int b = bh >> 4;

  const float* qrow = qkvT + (size_t)(0 * Csz + h * DHn + d) * NTOT + b * Tsz;
  const float* krow = qkvT + (size_t)(1 * Csz + h * DHn + d) * NTOT + b * Tsz;

  for (int t = tid; t < 4096; t += 256)
    bufA[t] = make_float2(qrow[t], krow[t]);

  fft4096(bufA, bufB, tid, -1.0f);

  float* outp = attn_raw + (size_t)bh * Fn;
  for (int f = tid; f < Fn; f += 256) {
    float2 zf = bufA[f];
    float2 zn = bufA[(4096 - f) & 4095];
    // Zc = conj(zn)
    float ar = zf.x + zn.x;   // A = Zf + Zc
    float ai = zf.y - zn.y;
    float br = zf.x - zn.x;   // B = Zf - Zc
    float bi = zf.y + zn.y;
    float val = 0.03125f * (ar * bi - ai * br);  // 0.25 * Im(conj(A)B) * (1/8)
    atomicAdd(&outp[f], val);
  }
}

// ---------------------------------------------------------------------------
// softmax over the F=2049 frequency bins, one block per (b,h).
// ---------------------------------------------------------------------------
__global__ __launch_bounds__(256)
void softmax_kernel(const float* __restrict__ raw, float* __restrict__ attn) {
  __shared__ float red[256];
  const int tid = threadIdx.x;
  const float* in = raw + (size_t)blockIdx.x * Fn;
  float* outp = attn + (size_t)blockIdx.x * Fn;

  float lmax = -3.4e38f;
  for (int f = tid; f < Fn; f += 256) lmax = fmaxf(lmax, in[f]);
  red[tid] = lmax;
  __syncthreads();
  for (int off = 128; off > 0; off >>= 1) {
    if (tid < off) red[tid] = fmaxf(red[tid], red[tid + off]);
    __syncthreads();
  }
  const float mx = red[0];
  __syncthreads();

  float lsum = 0.f;
  for (int f = tid; f < Fn; f += 256) lsum += __expf(in[f] - mx);
  red[tid] = lsum;
  __syncthreads();
  for (int off = 128; off > 0; off >>= 1) {
    if (tid < off) red[tid] += red[tid + off];
    __syncthreads();
  }
  const float inv = 1.0f / red[0];
  for (int f = tid; f < Fn; f += 256) outp[f] = __expf(in[f] - mx) * inv;
}

// ---------------------------------------------------------------------------
// v_filter: one block per (b,h,dpair). z = v[d0] + i*v[d1]; FFT; multiply each
// bin by the real symmetric filter a[f] (= attn[min(f, 4096-f)]); IFFT;
// y0 = Re/4096, y1 = Im/4096. Writes rows (h*64+d0, +1) of attn_outT, which
// aliases the dead q-region of qkvT.
// ---------------------------------------------------------------------------
__global__ __launch_bounds__(256)
void v_filter_kernel(float* __restrict__ qkvT, const float* __restrict__ attn) {
  __shared__ float2 bufA[4096];
  __shared__ float2 bufB[4096];
  const int tid = threadIdx.x;
  const int blk = blockIdx.x;          // (b*16+h)*32 + jp
  const int jp = blk & 31;
  const int bh = blk >> 5;
  const int h = bh & 15;
  const int b = bh >> 4;
  const int d0 = jp * 2;

  const float* v0 = qkvT + (size_t)(2 * Csz + h * DHn + d0) * NTOT + b * Tsz;
  const float* v1 = v0 + NTOT;

  for (int t = tid; t < 4096; t += 256)
    bufA[t] = make_float2(v0[t], v1[t]);

  fft4096(bufA, bufB, tid, -1.0f);

  const float* a = attn + (size_t)bh * Fn;
  for (int f = tid; f < 4096; f += 256) {
    int fm = (f <= 2048) ? f : (4096 - f);
    float s = a[fm];
    float2 z = bufA[f];
    bufA[f] = make_float2(z.x * s, z.y * s);
  }

  fft4096(bufA, bufB, tid, +1.0f);

  float* y0 = qkvT + (size_t)(h * DHn + d0) * NTOT + b * Tsz;   // q-region reuse
  float* y1 = y0 + NTOT;
  const float inv = 1.0f / 4096.0f;
  for (int t = tid; t < 4096; t += 256) {
    float2 z = bufA[t];
    y0[t] = z.x * inv;
    y1[t] = z.y * inv;
  }
}

// ---------------------------------------------------------------------------
// GEMM2: out[n][j] = sum_c At[c][n] * W_out[j][c] + b_out[j]
// At = attn_outT [1024][16384] (n-contig rows), W_out [1024][1024] K-contig.
// ---------------------------------------------------------------------------
__global__ __launch_bounds__(256)
void gemm2_kernel(const float* __restrict__ At, const float* __restrict__ W,
                  const float* __restrict__ bias, float* __restrict__ C) {
  __shared__ float As[16][132];   // [c][n]
  __shared__ float Bs[16][132];   // [c][j]
  const int tid = threadIdx.x;
  const int tx = tid & 15, ty = tid >> 4;
  const int n0 = blockIdx.y * 128, j0 = blockIdx.x * 128;
  const int ar = tid >> 4;             // 0..15 (c within tile)
  const int ac = (tid & 15) << 3;      // 0..120 (n within tile)
  const int lr = tid >> 1;             // 0..127 (j within tile)
  const int lc = (tid & 1) << 3;       // 0 or 8 (c within tile)

  float acc[8][8];
#pragma unroll
  for (int i = 0; i < 8; ++i)
#pragma unroll
    for (int j = 0; j < 8; ++j) acc[i][j] = 0.f;

  for (int k0 = 0; k0 < Csz; k0 += 16) {
    float4 a0 = *(const float4*)(At + (size_t)(k0 + ar) * NTOT + n0 + ac);
    float4 a1 = *(const float4*)(At + (size_t)(k0 + ar) * NTOT + n0 + ac + 4);
    float4 b0 = *(const float4*)(W + (size_t)(j0 + lr) * Csz + k0 + lc);
    float4 b1 = *(const float4*)(W + (size_t)(j0 + lr) * Csz + k0 + lc + 4);
    __syncthreads();
    *(float4*)&As[ar][ac]     = a0;
    *(float4*)&As[ar][ac + 4] = a1;
    Bs[lc + 0][lr] = b0.x; Bs[lc + 1][lr] = b0.y; Bs[lc + 2][lr] = b0.z; Bs[lc + 3][lr] = b0.w;
    Bs[lc + 4][lr] = b1.x; Bs[lc + 5][lr] = b1.y; Bs[lc + 6][lr] = b1.z; Bs[lc + 7][lr] = b1.w;
    __syncthreads();
#pragma unroll
    for (int kk = 0; kk < 16; ++kk) {
      float a[8], b[8];
      *(float4*)&a[0] = *(const float4*)&As[kk][ty * 8];
      *(float4*)&a[4] = *(const float4*)&As[kk][ty * 8 + 4];
      *(float4*)&b[0] = *(const float4*)&Bs[kk][tx * 8];
      *(float4*)&b[4] = *(const float4*)&Bs[kk][tx * 8 + 4];
#pragma unroll
      for (int i = 0; i < 8; ++i)
#pragma unroll
        for (int j = 0; j < 8; ++j) acc[i][j] = fmaf(a[i], b[j], acc[i][j]);
    }
  }
#pragma unroll
  for (int i = 0; i < 8; ++i) {
    float* cp = C + (size_t)(n0 + ty * 8 + i) * Csz + j0 + tx * 8;
#pragma unroll
    for (int j = 0; j < 8; ++j) cp[j] = acc[i][j] + bias[j0 + tx * 8 + j];
  }
}

// Zero a float buffer (graph-capture-safe alternative to hipMemsetAsync)
__global__ void zero_kernel(float* __restrict__ p, int n) {
  int i = blockIdx.x * blockDim.x + threadIdx.x;
  if (i < n) p[i] = 0.f;
}

// ---------------------------------------------------------------------------
extern "C" void kernel_launch(void* const* d_in, const int* in_sizes, int n_in,
                              void* d_out, int out_size, void* d_ws, size_t ws_size,
                              hipStream_t stream) {
  const float* x    = (const float*)d_in[0];   // [4,4096,1024]
  const float* Wqkv = (const float*)d_in[1];   // [3072,1024]
  const float* Wout = (const float*)d_in[2];   // [1024,1024]
  const float* bout = (const float*)d_in[3];   // [1024]
  float* out = (float*)d_out;                  // [16384,1024]

  float* qkvT     = (float*)d_ws;                         // [3072][16384]
  float* attn_raw = qkvT + (size_t)M3 * NTOT;             // [64][2049]
  float* attn     = attn_raw + (size_t)BHn * Fn;          // [64][2049]
  // attn_outT aliases qkvT rows [0,1024) (dead q region) after qk_cross.

  const int nraw = BHn * Fn;
  zero_kernel<<<(nraw + 255) / 256, 256, 0, stream>>>(attn_raw, nraw);

  gemm1_kernel<<<dim3(NTOT / 128, M3 / 128), 256, 0, stream>>>(Wqkv, x, qkvT);

  qk_cross_kernel<<<Bsz * Hn * DHn, 256, 0, stream>>>(qkvT, attn_raw);

  softmax_kernel<<<BHn, 256, 0, stream>>>(attn_raw, attn);

  v_filter_kernel<<<Bsz * Hn * (DHn / 2), 256, 0, stream>>>(qkvT, attn);

  gemm2_kernel<<<dim3(Csz / 128, NTOT / 128), 256, 0, stream>>>(qkvT, Wout, bout, out);
}

// Round 2
// 1782.353 us; speedup vs baseline: 1.0074x; 1.0074x over previous
//
#include <hip/hip_runtime.h>
#include <math.h>

// Problem constants
#define Bsz   4
#define Tsz   4096
#define Csz   1024
#define Hn    16
#define DHn   64
#define NTOT  (Bsz * Tsz)      // 16384 rows of x
#define M3    (3 * Csz)        // 3072
#define Fn    2049             // T/2 + 1
#define BHn   (Bsz * Hn)       // 64

typedef __bf16 bf16x8 __attribute__((ext_vector_type(8)));
typedef __bf16 bf16x4 __attribute__((ext_vector_type(4)));
typedef float  f32x4  __attribute__((ext_vector_type(4)));

// ---------------------------------------------------------------------------
// async global->LDS, 16B per lane. gptr is per-lane; lptr must be wave-uniform
// (HW writes lptr + lane*16).
// ---------------------------------------------------------------------------
__device__ __forceinline__ void gload_lds16(const void* g, void* l) {
  __builtin_amdgcn_global_load_lds(
      (const __attribute__((address_space(1))) void*)g,
      (__attribute__((address_space(3))) void*)l, 16, 0, 0);
}

// ---------------------------------------------------------------------------
// f32 -> (hi, lo) bf16 split, 4 elems/thread. hi = RNE(v), lo = RNE(v - hi).
// ---------------------------------------------------------------------------
__global__ __launch_bounds__(256)
void cvt_hilo_kernel(const float4* __restrict__ in, bf16x4* __restrict__ hi,
                     bf16x4* __restrict__ lo, int n4) {
  int i = blockIdx.x * blockDim.x + threadIdx.x;
  if (i >= n4) return;
  float4 v = in[i];
  bf16x4 h, l;
  h[0] = (__bf16)v.x; h[1] = (__bf16)v.y; h[2] = (__bf16)v.z; h[3] = (__bf16)v.w;
  l[0] = (__bf16)(v.x - (float)h[0]);
  l[1] = (__bf16)(v.y - (float)h[1]);
  l[2] = (__bf16)(v.z - (float)h[2]);
  l[3] = (__bf16)(v.w - (float)h[3]);
  hi[i] = h;
  lo[i] = l;
}

// ---------------------------------------------------------------------------
// GEMM1 via split-bf16 MFMA: qkvT[m][n] = sum_k W[m][k] * x[n][k]
//   W ~ (Whi+Wlo), x ~ (Xhi+Xlo); product = WhXh + WhXl + WlXh.
// 128x128 tile, 4 waves (2x2), each wave 64x64 = 4x4 frags of 16x16x32.
// LDS per k-step (BK=32): 4 tiles (Ahi,Alo,Bhi,Blo) of 128rows x 32bf16 = 8KB,
// layout [rowblock rb(8)][kchunk kc(4)][row16 r(16)] in 16B units so that the
// global_load_lds lane-linear write order == the fragment ds_read_b128 order.
// ---------------------------------------------------------------------------
__global__ __launch_bounds__(256)
void gemm1_mfma(const __bf16* __restrict__ Ahi, const __bf16* __restrict__ Alo,
                const __bf16* __restrict__ Bhi, const __bf16* __restrict__ Blo,
                float* __restrict__ C) {
  __shared__ char lds[32768];
  char* ldsAh = lds;
  char* ldsAl = lds + 8192;
  char* ldsBh = lds + 16384;
  char* ldsBl = lds + 24576;

  const int tid  = threadIdx.x;
  const int wid  = tid >> 6;        // wave 0..3
  const int lane = tid & 63;
  const int wm = wid >> 1, wn = wid & 1;
  const int m0 = blockIdx.y * 128;
  const int n0 = blockIdx.x * 128;

  const int r16 = lane & 15;        // row within 16-row block (staging)
  const int kc  = lane >> 4;        // k-chunk 0..3 (8 bf16 each)

  // staging global base pointers: wave stages rowblocks wid and wid+4
  const int aR0 = m0 + wid * 16 + r16;
  const int bR0 = n0 + wid * 16 + r16;
  const __bf16* pAh0 = Ahi + (size_t)aR0 * Csz + kc * 8;
  const __bf16* pAh1 = pAh0 + (size_t)64 * Csz;
  const __bf16* pAl0 = Alo + (size_t)aR0 * Csz + kc * 8;
  const __bf16* pAl1 = pAl0 + (size_t)64 * Csz;
  const __bf16* pBh0 = Bhi + (size_t)bR0 * Csz + kc * 8;
  const __bf16* pBh1 = pBh0 + (size_t)64 * Csz;
  const __bf16* pBl0 = Blo + (size_t)bR0 * Csz + kc * 8;
  const __bf16* pBl1 = pBl0 + (size_t)64 * Csz;

  // wave-uniform LDS dests (1 KB per rowblock)
  char* dAh0 = ldsAh + wid * 1024;  char* dAh1 = dAh0 + 4096;
  char* dAl0 = ldsAl + wid * 1024;  char* dAl1 = dAl0 + 4096;
  char* dBh0 = ldsBh + wid * 1024;  char* dBh1 = dBh0 + 4096;
  char* dBl0 = ldsBl + wid * 1024;  char* dBl1 = dBl0 + 4096;

  f32x4 acc[4][4];
#pragma unroll
  for (int i = 0; i < 4; ++i)
#pragma unroll
    for (int j = 0; j < 4; ++j) acc[i][j] = (f32x4)(0.f);

  for (int k0 = 0; k0 < Csz; k0 += 32) {
    __syncthreads();   // all waves done reading previous tile
    gload_lds16(pAh0 + k0, dAh0);
    gload_lds16(pAh1 + k0, dAh1);
    gload_lds16(pAl0 + k0, dAl0);
    gload_lds16(pAl1 + k0, dAl1);
    gload_lds16(pBh0 + k0, dBh0);
    gload_lds16(pBh1 + k0, dBh1);
    gload_lds16(pBl0 + k0, dBl0);
    gload_lds16(pBl1 + k0, dBl1);
    __syncthreads();   // compiler drains vmcnt(0) before barrier -> data ready

    bf16x8 ah[4], al[4], bh[4], bl[4];
#pragma unroll
    for (int f = 0; f < 4; ++f) {
      const int offA = (wm * 4 + f) * 1024 + lane * 16;
      ah[f] = *(const bf16x8*)(ldsAh + offA);
      al[f] = *(const bf16x8*)(ldsAl + offA);
      const int offB = (wn * 4 + f) * 1024 + lane * 16;
      bh[f] = *(const bf16x8*)(ldsBh + offB);
      bl[f] = *(const bf16x8*)(ldsBl + offB);
    }
#pragma unroll
    for (int fm = 0; fm < 4; ++fm)
#pragma unroll
      for (int fn = 0; fn < 4; ++fn) {
        acc[fm][fn] = __builtin_amdgcn_mfma_f32_16x16x32_bf16(ah[fm], bh[fn], acc[fm][fn], 0, 0, 0);
        acc[fm][fn] = __builtin_amdgcn_mfma_f32_16x16x32_bf16(ah[fm], bl[fn], acc[fm][fn], 0, 0, 0);
        acc[fm][fn] = __builtin_amdgcn_mfma_f32_16x16x32_bf16(al[fm], bh[fn], acc[fm][fn], 0, 0, 0);
      }
  }

  // epilogue: D row=(lane>>4)*4+r (m dim), col=lane&15 (n dim)
  const int cm = m0 + wm * 64 + (lane >> 4) * 4;
  const int cn = n0 + wn * 64 + (lane & 15);
#pragma unroll
  for (int fm = 0; fm < 4; ++fm)
#pragma unroll
    for (int r = 0; r < 4; ++r) {
      float* cp = C + (size_t)(cm + fm * 16 + r) * NTOT + cn;
#pragma unroll
      for (int fn = 0; fn < 4; ++fn) cp[fn * 16] = acc[fm][fn][r];
    }
}

// ---------------------------------------------------------------------------
// GEMM1 fallback (f32 vector) if workspace too small for hi/lo arrays.
// ---------------------------------------------------------------------------
__global__ __launch_bounds__(256)
void gemm1_kernel(const float* __restrict__ A, const float* __restrict__ B,
                  float* __restrict__ C) {
  __shared__ float As[16][132];
  __shared__ float Bs[16][132];
  const int tid = threadIdx.x;
  const int tx = tid & 15, ty = tid >> 4;
  const int m0 = blockIdx.y * 128, n0 = blockIdx.x * 128;
  const int lr = tid >> 1;
  const int lc = (tid & 1) << 3;

  float acc[8][8];
#pragma unroll
  for (int i = 0; i < 8; ++i)
#pragma unroll
    for (int j = 0; j < 8; ++j) acc[i][j] = 0.f;

  const float* Ap = A + (size_t)(m0 + lr) * Csz + lc;
  const float* Bp = B + (size_t)(n0 + lr) * Csz + lc;

  for (int k0 = 0; k0 < Csz; k0 += 16) {
    float4 a0 = *(const float4*)(Ap + k0);
    float4 a1 = *(const float4*)(Ap + k0 + 4);
    float4 b0 = *(const float4*)(Bp + k0);
    float4 b1 = *(const float4*)(Bp + k0 + 4);
    __syncthreads();
    As[lc + 0][lr] = a0.x; As[lc + 1][lr] = a0.y; As[lc + 2][lr] = a0.z; As[lc + 3][lr] = a0.w;
    As[lc + 4][lr] = a1.x; As[lc + 5][lr] = a1.y; As[lc + 6][lr] = a1.z; As[lc + 7][lr] = a1.w;
    Bs[lc + 0][lr] = b0.x; Bs[lc + 1][lr] = b0.y; Bs[lc + 2][lr] = b0.z; Bs[lc + 3][lr] = b0.w;
    Bs[lc + 4][lr] = b1.x; Bs[lc + 5][lr] = b1.y; Bs[lc + 6][lr] = b1.z; Bs[lc + 7][lr] = b1.w;
    __syncthreads();
#pragma unroll
    for (int kk = 0; kk < 16; ++kk) {
      float a[8], b[8];
      *(float4*)&a[0] = *(const float4*)&As[kk][ty * 8];
      *(float4*)&a[4] = *(const float4*)&As[kk][ty * 8 + 4];
      *(float4*)&b[0] = *(const float4*)&Bs[kk][tx * 8];
      *(float4*)&b[4] = *(const float4*)&Bs[kk][tx * 8 + 4];
#pragma unroll
      for (int i = 0; i < 8; ++i)
#pragma unroll
        for (int j = 0; j < 8; ++j) acc[i][j] = fmaf(a[i], b[j], acc[i][j]);
    }
  }
#pragma unroll
  for (int i = 0; i < 8; ++i) {
    float* cp = C + (size_t)(m0 + ty * 8 + i) * NTOT + n0 + tx * 8;
    *(float4*)cp       = make_float4(acc[i][0], acc[i][1], acc[i][2], acc[i][3]);
    *(float4*)(cp + 4) = make_float4(acc[i][4], acc[i][5], acc[i][6], acc[i][7]);
  }
}

// ---------------------------------------------------------------------------
// 4096-point complex Stockham FFT in LDS (radix-2, 12 stages, autosort).
// ---------------------------------------------------------------------------
__device__ __forceinline__ void fft4096(float2* X, float2* Y, int tid, float sign) {
  float2* src = X;
  float2* dst = Y;
#pragma unroll 1
  for (int stage = 0; stage < 12; ++stage) {
    const int s = 1 << stage;
    __syncthreads();
#pragma unroll
    for (int it = 0; it < 8; ++it) {
      const int idx = tid + (it << 8);
      const int sp = idx & ~(s - 1);
      float2 a = src[idx];
      float2 b = src[idx + 2048];
      float ang = sign * (6.28318530717958647692f / 4096.0f) * (float)sp;
      float sn, cs;
      __sincosf(ang, &sn, &cs);
      float2 sum = make_float2(a.x + b.x, a.y + b.y);
      float2 dif = make_float2(a.x - b.x, a.y - b.y);
      float2 tw  = make_float2(dif.x * cs - dif.y * sn, dif.x * sn + dif.y * cs);
      const int o = idx + sp;
      dst[o] = sum;
      dst[o + s] = tw;
    }
    float2* t = src; src = dst; dst = t;
  }
  __syncthreads();
}

// ---------------------------------------------------------------------------
// qk_cross: z = q + i*k, FFT, Re(conj(Q)K) = 0.25*Im(conj(Zf+Zc)(Zf-Zc)).
// Accumulate over d via atomicAdd. Includes scale 1/8.
// ---------------------------------------------------------------------------
__global__ __launch_bounds__(256)
void qk_cross_kernel(const float* __restrict__ qkvT, float* __restrict__ attn_raw) {
  __shared__ float2 bufA[4096];
  __shared__ float2 bufB[4096];
  const int tid = threadIdx.x;
  const int blk = blockIdx.x;
  const int d = blk & 63;
  const int bh = blk >> 6;
  const int h = bh & 15;
  const int b = bh >> 4;

  const float* qrow = qkvT + (size_t)(0 * Csz + h * DHn + d) * NTOT + b * Tsz;
  const float* krow = qkvT + (size_t)(1 * Csz + h * DHn + d) * NTOT + b * Tsz;

  for (int t = tid; t < 4096; t += 256)
    bufA[t] = make_float2(qrow[t], krow[t]);

  fft4096(bufA, bufB, tid, -1.0f);

  float* outp = attn_raw + (size_t)bh * Fn;
  for (int f = tid; f < Fn; f += 256) {
    float2 zf = bufA[f];
    float2 zn = bufA[(4096 - f) & 4095];
    float ar = zf.x + zn.x;
    float ai = zf.y - zn.y;
    float br = zf.x - zn.x;
    float bi = zf.y + zn.y;
    float val = 0.03125f * (ar * bi - ai * br);
    atomicAdd(&outp[f], val);
  }
}

// ---------------------------------------------------------------------------
__global__ __launch_bounds__(256)
void softmax_kernel(const float* __restrict__ raw, float* __restrict__ attn) {
  __shared__ float red[256];
  const int tid = threadIdx.x;
  const float* in = raw + (size_t)blockIdx.x * Fn;
  float* outp = attn + (size_t)blockIdx.x * Fn;

  float lmax = -3.4e38f;
  for (int f = tid; f < Fn; f += 256) lmax = fmaxf(lmax, in[f]);
  red[tid] = lmax;
  __syncthreads();
  for (int off = 128; off > 0; off >>= 1) {
    if (tid < off) red[tid] = fmaxf(red[tid], red[tid + off]);
    __syncthreads();
  }
  const float mx = red[0];
  __syncthreads();

  float lsum = 0.f;
  for (int f = tid; f < Fn; f += 256) lsum += __expf(in[f] - mx);
  red[tid] = lsum;
  __syncthreads();
  for (int off = 128; off > 0; off >>= 1) {
    if (tid < off) red[tid] += red[tid + off];
    __syncthreads();
  }
  const float inv = 1.0f / red[0];
  for (int f = tid; f < Fn; f += 256) outp[f] = __expf(in[f] - mx) * inv;
}

// ---------------------------------------------------------------------------
// v_filter: z = v[d0] + i*v[d1]; FFT; multiply by real symmetric filter a[f];
// IFFT; write y0,y1 into dead q-region of qkvT.
// ---------------------------------------------------------------------------
__global__ __launch_bounds__(256)
void v_filter_kernel(float* __restrict__ qkvT, const float* __restrict__ attn) {
  __shared__ float2 bufA[4096];
  __shared__ float2 bufB[4096];
  const int tid = threadIdx.x;
  const int blk = blockIdx.x;
  const int jp = blk & 31;
  const int bh = blk >> 5;
  const int h = bh & 15;
  const int b = bh >> 4;
  const int d0 = jp * 2;

  const float* v0 = qkvT + (size_t)(2 * Csz + h * DHn + d0) * NTOT + b * Tsz;
  const float* v1 = v0 + NTOT;

  for (int t = tid; t < 4096; t += 256)
    bufA[t] = make_float2(v0[t], v1[t]);

  fft4096(bufA, bufB, tid, -1.0f);

  const float* a = attn + (size_t)bh * Fn;
  for (int f = tid; f < 4096; f += 256) {
    int fm = (f <= 2048) ? f : (4096 - f);
    float s = a[fm];
    float2 z = bufA[f];
    bufA[f] = make_float2(z.x * s, z.y * s);
  }

  fft4096(bufA, bufB, tid, +1.0f);

  float* y0 = qkvT + (size_t)(h * DHn + d0) * NTOT + b * Tsz;
  float* y1 = y0 + NTOT;
  const float inv = 1.0f / 4096.0f;
  for (int t = tid; t < 4096; t += 256) {
    float2 z = bufA[t];
    y0[t] = z.x * inv;
    y1[t] = z.y * inv;
  }
}

// ---------------------------------------------------------------------------
// GEMM2: out[n][j] = sum_c At[c][n] * W_out[j][c] + b_out[j]
// ---------------------------------------------------------------------------
__global__ __launch_bounds__(256)
void gemm2_kernel(const float* __restrict__ At, const float* __restrict__ W,
                  const float* __restrict__ bias, float* __restrict__ C) {
  __shared__ float As[16][132];
  __shared__ float Bs[16][132];
  const int tid = threadIdx.x;
  const int tx = tid & 15, ty = tid >> 4;
  const int n0 = blockIdx.y * 128, j0 = blockIdx.x * 128;
  const int ar = tid >> 4;
  const int ac = (tid & 15) << 3;
  const int lr = tid >> 1;
  const int lc = (tid & 1) << 3;

  float acc[8][8];
#pragma unroll
  for (int i = 0; i < 8; ++i)
#pragma unroll
    for (int j = 0; j < 8; ++j) acc[i][j] = 0.f;

  for (int k0 = 0; k0 < Csz; k0 += 16) {
    float4 a0 = *(const float4*)(At + (size_t)(k0 + ar) * NTOT + n0 + ac);
    float4 a1 = *(const float4*)(At + (size_t)(k0 + ar) * NTOT + n0 + ac + 4);
    float4 b0 = *(const float4*)(W + (size_t)(j0 + lr) * Csz + k0 + lc);
    float4 b1 = *(const float4*)(W + (size_t)(j0 + lr) * Csz + k0 + lc + 4);
    __syncthreads();
    *(float4*)&As[ar][ac]     = a0;
    *(float4*)&As[ar][ac + 4] = a1;
    Bs[lc + 0][lr] = b0.x; Bs[lc + 1][lr] = b0.y; Bs[lc + 2][lr] = b0.z; Bs[lc + 3][lr] = b0.w;
    Bs[lc + 4][lr] = b1.x; Bs[lc + 5][lr] = b1.y; Bs[lc + 6][lr] = b1.z; Bs[lc + 7][lr] = b1.w;
    __syncthreads();
#pragma unroll
    for (int kk = 0; kk < 16; ++kk) {
      float a[8], b[8];
      *(float4*)&a[0] = *(const float4*)&As[kk][ty * 8];
      *(float4*)&a[4] = *(const float4*)&As[kk][ty * 8 + 4];
      *(float4*)&b[0] = *(const float4*)&Bs[kk][tx * 8];
      *(float4*)&b[4] = *(const float4*)&Bs[kk][tx * 8 + 4];
#pragma unroll
      for (int i = 0; i < 8; ++i)
#pragma unroll
        for (int j = 0; j < 8; ++j) acc[i][j] = fmaf(a[i], b[j], acc[i][j]);
    }
  }
#pragma unroll
  for (int i = 0; i < 8; ++i) {
    float* cp = C + (size_t)(n0 + ty * 8 + i) * Csz + j0 + tx * 8;
#pragma unroll
    for (int j = 0; j < 8; ++j) cp[j] = acc[i][j] + bias[j0 + tx * 8 + j];
  }
}

__global__ void zero_kernel(float* __restrict__ p, int n) {
  int i = blockIdx.x * blockDim.x + threadIdx.x;
  if (i < n) p[i] = 0.f;
}

// ---------------------------------------------------------------------------
extern "C" void kernel_launch(void* const* d_in, const int* in_sizes, int n_in,
                              void* d_out, int out_size, void* d_ws, size_t ws_size,
                              hipStream_t stream) {
  const float* x    = (const float*)d_in[0];   // [4,4096,1024]
  const float* Wqkv = (const float*)d_in[1];   // [3072,1024]
  const float* Wout = (const float*)d_in[2];   // [1024,1024]
  const float* bout = (const float*)d_in[3];   // [1024]
  float* out = (float*)d_out;                  // [16384,1024]

  char* ws = (char*)d_ws;
  float* qkvT     = (float*)ws;                               // 201326592 B
  float* attn_raw = (float*)(ws + 201326592ull);              // 524544 B
  float* attn     = (float*)(ws + 201851136ull);              // 524544 B
  __bf16* Whi     = (__bf16*)(ws + 202375680ull);             // 6291456 B
  __bf16* Wlo     = (__bf16*)(ws + 208667136ull);             // 6291456 B
  __bf16* Xhi     = (__bf16*)(ws + 214958592ull);             // 33554432 B
  __bf16* Xlo     = (__bf16*)(ws + 248513024ull);             // 33554432 B
  const size_t NEED_MFMA = 282067456ull;

  const int nraw = BHn * Fn;
  zero_kernel<<<(nraw + 255) / 256, 256, 0, stream>>>(attn_raw, nraw);

  if (ws_size >= NEED_MFMA) {
    cvt_hilo_kernel<<<3072, 256, 0, stream>>>((const float4*)Wqkv,
                                              (bf16x4*)Whi, (bf16x4*)Wlo, 786432);
    cvt_hilo_kernel<<<16384, 256, 0, stream>>>((const float4*)x,
                                               (bf16x4*)Xhi, (bf16x4*)Xlo, 4194304);
    gemm1_mfma<<<dim3(NTOT / 128, M3 / 128), 256, 0, stream>>>(Whi, Wlo, Xhi, Xlo, qkvT);
  } else {
    gemm1_kernel<<<dim3(NTOT / 128, M3 / 128), 256, 0, stream>>>(Wqkv, x, qkvT);
  }

  qk_cross_kernel<<<Bsz * Hn * DHn, 256, 0, stream>>>(qkvT, attn_raw);

  softmax_kernel<<<BHn, 256, 0, stream>>>(attn_raw, attn);

  v_filter_kernel<<<Bsz * Hn * (DHn / 2), 256, 0, stream>>>(qkvT, attn);

  gemm2_kernel<<<dim3(Csz / 128, NTOT / 128), 256, 0, stream>>>(qkvT, Wout, bout, out);
}

// Round 3
// 1149.421 us; speedup vs baseline: 1.5621x; 1.5507x over previous
//
#include <hip/hip_runtime.h>
#include <math.h>

// Problem constants
#define Bsz   4
#define Tsz   4096
#define Csz   1024
#define Hn    16
#define DHn   64
#define NTOT  (Bsz * Tsz)      // 16384 rows of x
#define M3    (3 * Csz)        // 3072
#define Fn    2049             // T/2 + 1
#define BHn   (Bsz * Hn)       // 64

typedef __bf16 bf16x8 __attribute__((ext_vector_type(8)));
typedef __bf16 bf16x4 __attribute__((ext_vector_type(4)));
typedef float  f32x4  __attribute__((ext_vector_type(4)));

// ---------------------------------------------------------------------------
// async global->LDS, 16B per lane. gptr per-lane; lptr wave-uniform
// (HW writes lptr + lane*16).
// ---------------------------------------------------------------------------
__device__ __forceinline__ void gload_lds16(const void* g, void* l) {
  __builtin_amdgcn_global_load_lds(
      (const __attribute__((address_space(1))) void*)g,
      (__attribute__((address_space(3))) void*)l, 16, 0, 0);
}

// ---------------------------------------------------------------------------
// f32 -> (hi, lo) bf16 split, 4 elems/thread. hi = RNE(v), lo = RNE(v - hi).
// ---------------------------------------------------------------------------
__global__ __launch_bounds__(256)
void cvt_hilo_kernel(const float4* __restrict__ in, bf16x4* __restrict__ hi,
                     bf16x4* __restrict__ lo, int n4) {
  int i = blockIdx.x * blockDim.x + threadIdx.x;
  if (i >= n4) return;
  float4 v = in[i];
  bf16x4 h, l;
  h[0] = (__bf16)v.x; h[1] = (__bf16)v.y; h[2] = (__bf16)v.z; h[3] = (__bf16)v.w;
  l[0] = (__bf16)(v.x - (float)h[0]);
  l[1] = (__bf16)(v.y - (float)h[1]);
  l[2] = (__bf16)(v.z - (float)h[2]);
  l[3] = (__bf16)(v.w - (float)h[3]);
  hi[i] = h;
  lo[i] = l;
}

// ---------------------------------------------------------------------------
// Split-bf16 MFMA GEMM: C[m][nbase+n] = sum_k A[m][k] * B[n][k]
//   A ~ (Ahi+Alo), B ~ (Bhi+Blo); product = AhBh + AhBl + AlBh.
// 128x128 tile, 4 waves (2x2), each wave 64x64 = 4x4 frags of 16x16x32.
// LDS per k-step (BK=32): 4 tiles of 128rows x 32bf16 = 8KB each; layout
// [rowblock(8)][kchunk(4)][row16(16)] x 16B so the global_load_lds lane-linear
// write order == the fragment ds_read_b128 order (no repack, no conflicts).
// B rows are panel-local (4096 rows); output column = nbase + panel col.
// ---------------------------------------------------------------------------
__global__ __launch_bounds__(256)
void gemm_mfma_split(const __bf16* __restrict__ Ahi, const __bf16* __restrict__ Alo,
                     const __bf16* __restrict__ Bhi, const __bf16* __restrict__ Blo,
                     float* __restrict__ C, int nbase) {
  __shared__ char lds[32768];
  char* ldsAh = lds;
  char* ldsAl = lds + 8192;
  char* ldsBh = lds + 16384;
  char* ldsBl = lds + 24576;

  const int tid  = threadIdx.x;
  const int wid  = tid >> 6;        // wave 0..3
  const int lane = tid & 63;
  const int wm = wid >> 1, wn = wid & 1;
  const int m0 = blockIdx.y * 128;
  const int n0 = blockIdx.x * 128;  // panel-local

  const int r16 = lane & 15;        // row within 16-row block (staging)
  const int kc  = lane >> 4;        // k-chunk 0..3 (8 bf16 each)

  const int aR0 = m0 + wid * 16 + r16;
  const int bR0 = n0 + wid * 16 + r16;
  const __bf16* pAh0 = Ahi + (size_t)aR0 * Csz + kc * 8;
  const __bf16* pAh1 = pAh0 + (size_t)64 * Csz;
  const __bf16* pAl0 = Alo + (size_t)aR0 * Csz + kc * 8;
  const __bf16* pAl1 = pAl0 + (size_t)64 * Csz;
  const __bf16* pBh0 = Bhi + (size_t)bR0 * Csz + kc * 8;
  const __bf16* pBh1 = pBh0 + (size_t)64 * Csz;
  const __bf16* pBl0 = Blo + (size_t)bR0 * Csz + kc * 8;
  const __bf16* pBl1 = pBl0 + (size_t)64 * Csz;

  char* dAh0 = ldsAh + wid * 1024;  char* dAh1 = dAh0 + 4096;
  char* dAl0 = ldsAl + wid * 1024;  char* dAl1 = dAl0 + 4096;
  char* dBh0 = ldsBh + wid * 1024;  char* dBh1 = dBh0 + 4096;
  char* dBl0 = ldsBl + wid * 1024;  char* dBl1 = dBl0 + 4096;

  f32x4 acc[4][4];
#pragma unroll
  for (int i = 0; i < 4; ++i)
#pragma unroll
    for (int j = 0; j < 4; ++j) acc[i][j] = (f32x4)(0.f);

  for (int k0 = 0; k0 < Csz; k0 += 32) {
    __syncthreads();   // all waves done reading previous tile
    gload_lds16(pAh0 + k0, dAh0);
    gload_lds16(pAh1 + k0, dAh1);
    gload_lds16(pAl0 + k0, dAl0);
    gload_lds16(pAl1 + k0, dAl1);
    gload_lds16(pBh0 + k0, dBh0);
    gload_lds16(pBh1 + k0, dBh1);
    gload_lds16(pBl0 + k0, dBl0);
    gload_lds16(pBl1 + k0, dBl1);
    __syncthreads();   // vmcnt(0) drained before barrier -> tile ready

    bf16x8 ah[4], al[4], bh[4], bl[4];
#pragma unroll
    for (int f = 0; f < 4; ++f) {
      const int offA = (wm * 4 + f) * 1024 + lane * 16;
      ah[f] = *(const bf16x8*)(ldsAh + offA);
      al[f] = *(const bf16x8*)(ldsAl + offA);
      const int offB = (wn * 4 + f) * 1024 + lane * 16;
      bh[f] = *(const bf16x8*)(ldsBh + offB);
      bl[f] = *(const bf16x8*)(ldsBl + offB);
    }
#pragma unroll
    for (int fm = 0; fm < 4; ++fm)
#pragma unroll
      for (int fn = 0; fn < 4; ++fn) {
        acc[fm][fn] = __builtin_amdgcn_mfma_f32_16x16x32_bf16(ah[fm], bh[fn], acc[fm][fn], 0, 0, 0);
        acc[fm][fn] = __builtin_amdgcn_mfma_f32_16x16x32_bf16(ah[fm], bl[fn], acc[fm][fn], 0, 0, 0);
        acc[fm][fn] = __builtin_amdgcn_mfma_f32_16x16x32_bf16(al[fm], bh[fn], acc[fm][fn], 0, 0, 0);
      }
  }

  // D layout (m89): row(m) = (lane>>4)*4 + r, col(n) = lane&15
  const int cm = m0 + wm * 64 + (lane >> 4) * 4;
  const int cn = nbase + n0 + wn * 64 + (lane & 15);
#pragma unroll
  for (int fm = 0; fm < 4; ++fm)
#pragma unroll
    for (int r = 0; r < 4; ++r) {
      float* cp = C + (size_t)(cm + fm * 16 + r) * NTOT + cn;
#pragma unroll
      for (int fn = 0; fn < 4; ++fn) cp[fn * 16] = acc[fm][fn][r];
    }
}

// ---------------------------------------------------------------------------
// 4096-point complex Stockham FFT in LDS (radix-2, 12 stages, autosort).
// ---------------------------------------------------------------------------
__device__ __forceinline__ void fft4096(float2* X, float2* Y, int tid, float sign) {
  float2* src = X;
  float2* dst = Y;
#pragma unroll 1
  for (int stage = 0; stage < 12; ++stage) {
    const int s = 1 << stage;
    __syncthreads();
#pragma unroll
    for (int it = 0; it < 8; ++it) {
      const int idx = tid + (it << 8);
      const int sp = idx & ~(s - 1);
      float2 a = src[idx];
      float2 b = src[idx + 2048];
      float ang = sign * (6.28318530717958647692f / 4096.0f) * (float)sp;
      float sn, cs;
      __sincosf(ang, &sn, &cs);
      float2 sum = make_float2(a.x + b.x, a.y + b.y);
      float2 dif = make_float2(a.x - b.x, a.y - b.y);
      float2 tw  = make_float2(dif.x * cs - dif.y * sn, dif.x * sn + dif.y * cs);
      const int o = idx + sp;
      dst[o] = sum;
      dst[o + s] = tw;
    }
    float2* t = src; src = dst; dst = t;
  }
  __syncthreads();
}

// ---------------------------------------------------------------------------
// qk_cross: z = q + i*k, FFT, Re(conj(Q)K) = 0.25*Im(conj(Zf+Zc)(Zf-Zc)).
// qkT: [2048][16384]; rows 0..1023 = q (c-major), rows 1024..2047 = k.
// Accumulate over d via atomicAdd. Includes scale 1/8.
// ---------------------------------------------------------------------------
__global__ __launch_bounds__(256)
void qk_cross_kernel(const float* __restrict__ qkT, float* __restrict__ attn_raw) {
  __shared__ float2 bufA[4096];
  __shared__ float2 bufB[4096];
  const int tid = threadIdx.x;
  const int blk = blockIdx.x;
  const int d = blk & 63;
  const int bh = blk >> 6;
  const int h = bh & 15;
  const int b = bh >> 4;

  const float* qrow = qkT + (size_t)(h * DHn + d) * NTOT + b * Tsz;
  const float* krow = qkT + (size_t)(Csz + h * DHn + d) * NTOT + b * Tsz;

  for (int t = tid; t < 4096; t += 256)
    bufA[t] = make_float2(qrow[t], krow[t]);

  fft4096(bufA, bufB, tid, -1.0f);

  float* outp = attn_raw + (size_t)bh * Fn;
  for (int f = tid; f < Fn; f += 256) {
    float2 zf = bufA[f];
    float2 zn = bufA[(4096 - f) & 4095];
    float ar = zf.x + zn.x;
    float ai = zf.y - zn.y;
    float br = zf.x - zn.x;
    float bi = zf.y + zn.y;
    float val = 0.03125f * (ar * bi - ai * br);
    atomicAdd(&outp[f], val);
  }
}

// ---------------------------------------------------------------------------
__global__ __launch_bounds__(256)
void softmax_kernel(const float* __restrict__ raw, float* __restrict__ attn) {
  __shared__ float red[256];
  const int tid = threadIdx.x;
  const float* in = raw + (size_t)blockIdx.x * Fn;
  float* outp = attn + (size_t)blockIdx.x * Fn;

  float lmax = -3.4e38f;
  for (int f = tid; f < Fn; f += 256) lmax = fmaxf(lmax, in[f]);
  red[tid] = lmax;
  __syncthreads();
  for (int off = 128; off > 0; off >>= 1) {
    if (tid < off) red[tid] = fmaxf(red[tid], red[tid + off]);
    __syncthreads();
  }
  const float mx = red[0];
  __syncthreads();

  float lsum = 0.f;
  for (int f = tid; f < Fn; f += 256) lsum += __expf(in[f] - mx);
  red[tid] = lsum;
  __syncthreads();
  for (int off = 128; off > 0; off >>= 1) {
    if (tid < off) red[tid] += red[tid + off];
    __syncthreads();
  }
  const float inv = 1.0f / red[0];
  for (int f = tid; f < Fn; f += 256) outp[f] = __expf(in[f] - mx) * inv;
}

// ---------------------------------------------------------------------------
// v_filter: z = v[d0] + i*v[d1]; FFT; multiply by real symmetric filter a[f];
// IFFT; write y0,y1 to vbarT.
// ---------------------------------------------------------------------------
__global__ __launch_bounds__(256)
void v_filter_kernel(const float* __restrict__ vT, float* __restrict__ vbarT,
                     const float* __restrict__ attn) {
  __shared__ float2 bufA[4096];
  __shared__ float2 bufB[4096];
  const int tid = threadIdx.x;
  const int blk = blockIdx.x;
  const int jp = blk & 31;
  const int bh = blk >> 5;
  const int h = bh & 15;
  const int b = bh >> 4;
  const int d0 = jp * 2;

  const float* v0 = vT + (size_t)(h * DHn + d0) * NTOT + b * Tsz;
  const float* v1 = v0 + NTOT;

  for (int t = tid; t < 4096; t += 256)
    bufA[t] = make_float2(v0[t], v1[t]);

  fft4096(bufA, bufB, tid, -1.0f);

  const float* a = attn + (size_t)bh * Fn;
  for (int f = tid; f < 4096; f += 256) {
    int fm = (f <= 2048) ? f : (4096 - f);
    float s = a[fm];
    float2 z = bufA[f];
    bufA[f] = make_float2(z.x * s, z.y * s);
  }

  fft4096(bufA, bufB, tid, +1.0f);

  float* y0 = vbarT + (size_t)(h * DHn + d0) * NTOT + b * Tsz;
  float* y1 = y0 + NTOT;
  const float inv = 1.0f / 4096.0f;
  for (int t = tid; t < 4096; t += 256) {
    float2 z = bufA[t];
    y0[t] = z.x * inv;
    y1[t] = z.y * inv;
  }
}

// ---------------------------------------------------------------------------
// GEMM2: out[n][j] = sum_c At[c][n] * W_out[j][c] + b_out[j]
// ---------------------------------------------------------------------------
__global__ __launch_bounds__(256)
void gemm2_kernel(const float* __restrict__ At, const float* __restrict__ W,
                  const float* __restrict__ bias, float* __restrict__ C) {
  __shared__ float As[16][132];
  __shared__ float Bs[16][132];
  const int tid = threadIdx.x;
  const int tx = tid & 15, ty = tid >> 4;
  const int n0 = blockIdx.y * 128, j0 = blockIdx.x * 128;
  const int ar = tid >> 4;
  const int ac = (tid & 15) << 3;
  const int lr = tid >> 1;
  const int lc = (tid & 1) << 3;

  float acc[8][8];
#pragma unroll
  for (int i = 0; i < 8; ++i)
#pragma unroll
    for (int j = 0; j < 8; ++j) acc[i][j] = 0.f;

  for (int k0 = 0; k0 < Csz; k0 += 16) {
    float4 a0 = *(const float4*)(At + (size_t)(k0 + ar) * NTOT + n0 + ac);
    float4 a1 = *(const float4*)(At + (size_t)(k0 + ar) * NTOT + n0 + ac + 4);
    float4 b0 = *(const float4*)(W + (size_t)(j0 + lr) * Csz + k0 + lc);
    float4 b1 = *(const float4*)(W + (size_t)(j0 + lr) * Csz + k0 + lc + 4);
    __syncthreads();
    *(float4*)&As[ar][ac]     = a0;
    *(float4*)&As[ar][ac + 4] = a1;
    Bs[lc + 0][lr] = b0.x; Bs[lc + 1][lr] = b0.y; Bs[lc + 2][lr] = b0.z; Bs[lc + 3][lr] = b0.w;
    Bs[lc + 4][lr] = b1.x; Bs[lc + 5][lr] = b1.y; Bs[lc + 6][lr] = b1.z; Bs[lc + 7][lr] = b1.w;
    __syncthreads();
#pragma unroll
    for (int kk = 0; kk < 16; ++kk) {
      float a[8], b[8];
      *(float4*)&a[0] = *(const float4*)&As[kk][ty * 8];
      *(float4*)&a[4] = *(const float4*)&As[kk][ty * 8 + 4];
      *(float4*)&b[0] = *(const float4*)&Bs[kk][tx * 8];
      *(float4*)&b[4] = *(const float4*)&Bs[kk][tx * 8 + 4];
#pragma unroll
      for (int i = 0; i < 8; ++i)
#pragma unroll
        for (int j = 0; j < 8; ++j) acc[i][j] = fmaf(a[i], b[j], acc[i][j]);
    }
  }
#pragma unroll
  for (int i = 0; i < 8; ++i) {
    float* cp = C + (size_t)(n0 + ty * 8 + i) * Csz + j0 + tx * 8;
#pragma unroll
    for (int j = 0; j < 8; ++j) cp[j] = acc[i][j] + bias[j0 + tx * 8 + j];
  }
}

__global__ void zero_kernel(float* __restrict__ p, int n) {
  int i = blockIdx.x * blockDim.x + threadIdx.x;
  if (i < n) p[i] = 0.f;
}

// ---------------------------------------------------------------------------
// Workspace layout (peak 164,626,944 B — fits the >=202 MB proven by round 1):
//   [0,           134217728)  R1: phase A/B = qkT [2048][16384] f32
//                             phase C: vT [1024][16384] overwrites q-half
//                             phase D: vbarT [1024][16384] overwrites k-half
//   [134217728,  134742272)   attn_raw [64][2049] f32
//   [134742272,  135266816)   attn     [64][2049] f32
//   [135266816,  141558272)   Whi [3072][1024] bf16
//   [141558272,  147849728)   Wlo
//   [147849728,  156238336)   Xhi panel [4096][1024] bf16 (reused 8x)
//   [156238336,  164626944)   Xlo panel
// ---------------------------------------------------------------------------
extern "C" void kernel_launch(void* const* d_in, const int* in_sizes, int n_in,
                              void* d_out, int out_size, void* d_ws, size_t ws_size,
                              hipStream_t stream) {
  const float* x    = (const float*)d_in[0];   // [4,4096,1024]
  const float* Wqkv = (const float*)d_in[1];   // [3072,1024]
  const float* Wout = (const float*)d_in[2];   // [1024,1024]
  const float* bout = (const float*)d_in[3];   // [1024]
  float* out = (float*)d_out;                  // [16384,1024]

  char* ws = (char*)d_ws;
  float* qkT      = (float*)ws;
  float* vT       = (float*)ws;
  float* vbarT    = (float*)(ws + 67108864ull);
  float* attn_raw = (float*)(ws + 134217728ull);
  float* attn     = (float*)(ws + 134742272ull);
  __bf16* Whi     = (__bf16*)(ws + 135266816ull);
  __bf16* Wlo     = (__bf16*)(ws + 141558272ull);
  __bf16* Xhi     = (__bf16*)(ws + 147849728ull);
  __bf16* Xlo     = (__bf16*)(ws + 156238336ull);

  const int nraw = BHn * Fn;
  zero_kernel<<<(nraw + 255) / 256, 256, 0, stream>>>(attn_raw, nraw);

  // W -> hi/lo (all 3072 rows)
  cvt_hilo_kernel<<<3072, 256, 0, stream>>>((const float4*)Wqkv,
                                            (bf16x4*)Whi, (bf16x4*)Wlo, 786432);

  // Phase A: q,k rows (2048) x all columns, panel by panel
  for (int p = 0; p < 4; ++p) {
    cvt_hilo_kernel<<<4096, 256, 0, stream>>>((const float4*)(x + (size_t)p * 4194304),
                                              (bf16x4*)Xhi, (bf16x4*)Xlo, 1048576);
    gemm_mfma_split<<<dim3(32, 16), 256, 0, stream>>>(Whi, Wlo, Xhi, Xlo, qkT, p * 4096);
  }

  qk_cross_kernel<<<Bsz * Hn * DHn, 256, 0, stream>>>(qkT, attn_raw);
  softmax_kernel<<<BHn, 256, 0, stream>>>(attn_raw, attn);

  // Phase C: v rows (1024) — q,k are dead; vT overwrites q-half of R1
  for (int p = 0; p < 4; ++p) {
    cvt_hilo_kernel<<<4096, 256, 0, stream>>>((const float4*)(x + (size_t)p * 4194304),
                                              (bf16x4*)Xhi, (bf16x4*)Xlo, 1048576);
    gemm_mfma_split<<<dim3(32, 8), 256, 0, stream>>>(Whi + 2048 * Csz, Wlo + 2048 * Csz,
                                                     Xhi, Xlo, vT, p * 4096);
  }

  v_filter_kernel<<<Bsz * Hn * (DHn / 2), 256, 0, stream>>>(vT, vbarT, attn);

  gemm2_kernel<<<dim3(Csz / 128, NTOT / 128), 256, 0, stream>>>(vbarT, Wout, bout, out);
}

// Round 4
// 908.724 us; speedup vs baseline: 1.9758x; 1.2649x over previous
//
#include <hip/hip_runtime.h>
#include <math.h>

// Problem constants
#define Bsz   4
#define Tsz   4096
#define Csz   1024
#define Hn    16
#define DHn   64
#define NTOT  (Bsz * Tsz)      // 16384 rows of x
#define M3    (3 * Csz)        // 3072
#define Fn    2049             // T/2 + 1
#define BHn   (Bsz * Hn)       // 64

typedef __bf16 bf16x8 __attribute__((ext_vector_type(8)));
typedef __bf16 bf16x4 __attribute__((ext_vector_type(4)));
typedef float  f32x4  __attribute__((ext_vector_type(4)));

// ---------------------------------------------------------------------------
// async global->LDS, 16B per lane. gptr per-lane; lptr wave-uniform
// (HW writes lptr + lane*16).
// ---------------------------------------------------------------------------
__device__ __forceinline__ void gload_lds16(const void* g, void* l) {
  __builtin_amdgcn_global_load_lds(
      (const __attribute__((address_space(1))) void*)g,
      (__attribute__((address_space(3))) void*)l, 16, 0, 0);
}

// ---------------------------------------------------------------------------
// f32 -> (hi, lo) bf16 split, 4 elems/thread. hi = RNE(v), lo = RNE(v - hi).
// ---------------------------------------------------------------------------
__global__ __launch_bounds__(256)
void cvt_hilo_kernel(const float4* __restrict__ in, bf16x4* __restrict__ hi,
                     bf16x4* __restrict__ lo, int n4) {
  int i = blockIdx.x * blockDim.x + threadIdx.x;
  if (i >= n4) return;
  float4 v = in[i];
  bf16x4 h, l;
  h[0] = (__bf16)v.x; h[1] = (__bf16)v.y; h[2] = (__bf16)v.z; h[3] = (__bf16)v.w;
  l[0] = (__bf16)(v.x - (float)h[0]);
  l[1] = (__bf16)(v.y - (float)h[1]);
  l[2] = (__bf16)(v.z - (float)h[2]);
  l[3] = (__bf16)(v.w - (float)h[3]);
  hi[i] = h;
  lo[i] = l;
}

// ---------------------------------------------------------------------------
// Transpose + hi/lo convert: src [1024][16384] f32 -> hi/lo [16384][1024] bf16.
// 64x64 tiles via LDS; padded [64][65] keeps banks 2-way (free on CDNA4).
// ---------------------------------------------------------------------------
__global__ __launch_bounds__(256)
void transpose_cvt_kernel(const float* __restrict__ src,
                          __bf16* __restrict__ hi, __bf16* __restrict__ lo) {
  __shared__ float tile[64][65];
  const int tid = threadIdx.x;
  const int n0 = blockIdx.x * 64;
  const int c0 = blockIdx.y * 64;
  const int col = tid & 63;
  const int row4 = tid >> 6;   // 0..3, constant per wave
#pragma unroll
  for (int i = 0; i < 16; ++i) {
    const int r = i * 4 + row4;
    tile[r][col] = src[(size_t)(c0 + r) * NTOT + n0 + col];
  }
  __syncthreads();
#pragma unroll
  for (int i = 0; i < 16; ++i) {
    const int n = i * 4 + row4;
    const float v = tile[col][n];
    const __bf16 h = (__bf16)v;
    const __bf16 l = (__bf16)(v - (float)h);
    hi[(size_t)(n0 + n) * Csz + c0 + col] = h;
    lo[(size_t)(n0 + n) * Csz + c0 + col] = l;
  }
}

// ---------------------------------------------------------------------------
// Split-bf16 MFMA GEMM: C[m][nbase+n] = sum_k A[m][k] * B[n][k]
//   A ~ (Ahi+Alo), B ~ (Bhi+Blo); product = AhBh + AhBl + AlBh.
// 128x128 tile, 4 waves (2x2), each wave 64x64 = 4x4 frags of 16x16x32.
// LDS per k-step (BK=32): 4 tiles of 128rows x 32bf16 = 8KB each; layout
// [rowblock(8)][kchunk(4)][row16(16)] x 16B so the global_load_lds lane-linear
// write order == the fragment ds_read_b128 order (no repack, no conflicts).
// C row stride = NTOT (transposed-output variant for gemm1).
// ---------------------------------------------------------------------------
__global__ __launch_bounds__(256)
void gemm_mfma_split(const __bf16* __restrict__ Ahi, const __bf16* __restrict__ Alo,
                     const __bf16* __restrict__ Bhi, const __bf16* __restrict__ Blo,
                     float* __restrict__ C, int nbase) {
  __shared__ char lds[32768];
  char* ldsAh = lds;
  char* ldsAl = lds + 8192;
  char* ldsBh = lds + 16384;
  char* ldsBl = lds + 24576;

  const int tid  = threadIdx.x;
  const int wid  = tid >> 6;
  const int lane = tid & 63;
  const int wm = wid >> 1, wn = wid & 1;
  const int m0 = blockIdx.y * 128;
  const int n0 = blockIdx.x * 128;

  const int r16 = lane & 15;
  const int kc  = lane >> 4;

  const int aR0 = m0 + wid * 16 + r16;
  const int bR0 = n0 + wid * 16 + r16;
  const __bf16* pAh0 = Ahi + (size_t)aR0 * Csz + kc * 8;
  const __bf16* pAh1 = pAh0 + (size_t)64 * Csz;
  const __bf16* pAl0 = Alo + (size_t)aR0 * Csz + kc * 8;
  const __bf16* pAl1 = pAl0 + (size_t)64 * Csz;
  const __bf16* pBh0 = Bhi + (size_t)bR0 * Csz + kc * 8;
  const __bf16* pBh1 = pBh0 + (size_t)64 * Csz;
  const __bf16* pBl0 = Blo + (size_t)bR0 * Csz + kc * 8;
  const __bf16* pBl1 = pBl0 + (size_t)64 * Csz;

  char* dAh0 = ldsAh + wid * 1024;  char* dAh1 = dAh0 + 4096;
  char* dAl0 = ldsAl + wid * 1024;  char* dAl1 = dAl0 + 4096;
  char* dBh0 = ldsBh + wid * 1024;  char* dBh1 = dBh0 + 4096;
  char* dBl0 = ldsBl + wid * 1024;  char* dBl1 = dBl0 + 4096;

  f32x4 acc[4][4];
#pragma unroll
  for (int i = 0; i < 4; ++i)
#pragma unroll
    for (int j = 0; j < 4; ++j) acc[i][j] = (f32x4)(0.f);

  for (int k0 = 0; k0 < Csz; k0 += 32) {
    __syncthreads();
    gload_lds16(pAh0 + k0, dAh0);
    gload_lds16(pAh1 + k0, dAh1);
    gload_lds16(pAl0 + k0, dAl0);
    gload_lds16(pAl1 + k0, dAl1);
    gload_lds16(pBh0 + k0, dBh0);
    gload_lds16(pBh1 + k0, dBh1);
    gload_lds16(pBl0 + k0, dBl0);
    gload_lds16(pBl1 + k0, dBl1);
    __syncthreads();

    bf16x8 ah[4], al[4], bh[4], bl[4];
#pragma unroll
    for (int f = 0; f < 4; ++f) {
      const int offA = (wm * 4 + f) * 1024 + lane * 16;
      ah[f] = *(const bf16x8*)(ldsAh + offA);
      al[f] = *(const bf16x8*)(ldsAl + offA);
      const int offB = (wn * 4 + f) * 1024 + lane * 16;
      bh[f] = *(const bf16x8*)(ldsBh + offB);
      bl[f] = *(const bf16x8*)(ldsBl + offB);
    }
#pragma unroll
    for (int fm = 0; fm < 4; ++fm)
#pragma unroll
      for (int fn = 0; fn < 4; ++fn) {
        acc[fm][fn] = __builtin_amdgcn_mfma_f32_16x16x32_bf16(ah[fm], bh[fn], acc[fm][fn], 0, 0, 0);
        acc[fm][fn] = __builtin_amdgcn_mfma_f32_16x16x32_bf16(ah[fm], bl[fn], acc[fm][fn], 0, 0, 0);
        acc[fm][fn] = __builtin_amdgcn_mfma_f32_16x16x32_bf16(al[fm], bh[fn], acc[fm][fn], 0, 0, 0);
      }
  }

  const int cm = m0 + wm * 64 + (lane >> 4) * 4;
  const int cn = nbase + n0 + wn * 64 + (lane & 15);
#pragma unroll
  for (int fm = 0; fm < 4; ++fm)
#pragma unroll
    for (int r = 0; r < 4; ++r) {
      float* cp = C + (size_t)(cm + fm * 16 + r) * NTOT + cn;
#pragma unroll
      for (int fn = 0; fn < 4; ++fn) cp[fn * 16] = acc[fm][fn][r];
    }
}

// ---------------------------------------------------------------------------
// gemm2_mfma: out[m][j] = sum_c A[m][c]*B[j][c] + bias[j], row stride Csz.
// Same structure as gemm_mfma_split; A = VT hi/lo [16384][1024],
// B = Wout hi/lo [1024][1024].
// ---------------------------------------------------------------------------
__global__ __launch_bounds__(256)
void gemm2_mfma(const __bf16* __restrict__ Ahi, const __bf16* __restrict__ Alo,
                const __bf16* __restrict__ Bhi, const __bf16* __restrict__ Blo,
                const float* __restrict__ bias, float* __restrict__ C) {
  __shared__ char lds[32768];
  char* ldsAh = lds;
  char* ldsAl = lds + 8192;
  char* ldsBh = lds + 16384;
  char* ldsBl = lds + 24576;

  const int tid  = threadIdx.x;
  const int wid  = tid >> 6;
  const int lane = tid & 63;
  const int wm = wid >> 1, wn = wid & 1;
  const int m0 = blockIdx.y * 128;
  const int n0 = blockIdx.x * 128;

  const int r16 = lane & 15;
  const int kc  = lane >> 4;

  const int aR0 = m0 + wid * 16 + r16;
  const int bR0 = n0 + wid * 16 + r16;
  const __bf16* pAh0 = Ahi + (size_t)aR0 * Csz + kc * 8;
  const __bf16* pAh1 = pAh0 + (size_t)64 * Csz;
  const __bf16* pAl0 = Alo + (size_t)aR0 * Csz + kc * 8;
  const __bf16* pAl1 = pAl0 + (size_t)64 * Csz;
  const __bf16* pBh0 = Bhi + (size_t)bR0 * Csz + kc * 8;
  const __bf16* pBh1 = pBh0 + (size_t)64 * Csz;
  const __bf16* pBl0 = Blo + (size_t)bR0 * Csz + kc * 8;
  const __bf16* pBl1 = pBl0 + (size_t)64 * Csz;

  char* dAh0 = ldsAh + wid * 1024;  char* dAh1 = dAh0 + 4096;
  char* dAl0 = ldsAl + wid * 1024;  char* dAl1 = dAl0 + 4096;
  char* dBh0 = ldsBh + wid * 1024;  char* dBh1 = dBh0 + 4096;
  char* dBl0 = ldsBl + wid * 1024;  char* dBl1 = dBl0 + 4096;

  f32x4 acc[4][4];
#pragma unroll
  for (int i = 0; i < 4; ++i)
#pragma unroll
    for (int j = 0; j < 4; ++j) acc[i][j] = (f32x4)(0.f);

  for (int k0 = 0; k0 < Csz; k0 += 32) {
    __syncthreads();
    gload_lds16(pAh0 + k0, dAh0);
    gload_lds16(pAh1 + k0, dAh1);
    gload_lds16(pAl0 + k0, dAl0);
    gload_lds16(pAl1 + k0, dAl1);
    gload_lds16(pBh0 + k0, dBh0);
    gload_lds16(pBh1 + k0, dBh1);
    gload_lds16(pBl0 + k0, dBl0);
    gload_lds16(pBl1 + k0, dBl1);
    __syncthreads();

    bf16x8 ah[4], al[4], bh[4], bl[4];
#pragma unroll
    for (int f = 0; f < 4; ++f) {
      const int offA = (wm * 4 + f) * 1024 + lane * 16;
      ah[f] = *(const bf16x8*)(ldsAh + offA);
      al[f] = *(const bf16x8*)(ldsAl + offA);
      const int offB = (wn * 4 + f) * 1024 + lane * 16;
      bh[f] = *(const bf16x8*)(ldsBh + offB);
      bl[f] = *(const bf16x8*)(ldsBl + offB);
    }
#pragma unroll
    for (int fm = 0; fm < 4; ++fm)
#pragma unroll
      for (int fn = 0; fn < 4; ++fn) {
        acc[fm][fn] = __builtin_amdgcn_mfma_f32_16x16x32_bf16(ah[fm], bh[fn], acc[fm][fn], 0, 0, 0);
        acc[fm][fn] = __builtin_amdgcn_mfma_f32_16x16x32_bf16(ah[fm], bl[fn], acc[fm][fn], 0, 0, 0);
        acc[fm][fn] = __builtin_amdgcn_mfma_f32_16x16x32_bf16(al[fm], bh[fn], acc[fm][fn], 0, 0, 0);
      }
  }

  const int cm = m0 + wm * 64 + (lane >> 4) * 4;
  const int cn = n0 + wn * 64 + (lane & 15);
  float bb[4];
#pragma unroll
  for (int fn = 0; fn < 4; ++fn) bb[fn] = bias[cn + fn * 16];
#pragma unroll
  for (int fm = 0; fm < 4; ++fm)
#pragma unroll
    for (int r = 0; r < 4; ++r) {
      float* cp = C + (size_t)(cm + fm * 16 + r) * Csz + cn;
#pragma unroll
      for (int fn = 0; fn < 4; ++fn) cp[fn * 16] = acc[fm][fn][r] + bb[fn];
    }
}

// ---------------------------------------------------------------------------
// 4096-point complex Stockham FFT in LDS (radix-2, 12 stages, autosort).
// ---------------------------------------------------------------------------
__device__ __forceinline__ void fft4096(float2* X, float2* Y, int tid, float sign) {
  float2* src = X;
  float2* dst = Y;
#pragma unroll 1
  for (int stage = 0; stage < 12; ++stage) {
    const int s = 1 << stage;
    __syncthreads();
#pragma unroll
    for (int it = 0; it < 8; ++it) {
      const int idx = tid + (it << 8);
      const int sp = idx & ~(s - 1);
      float2 a = src[idx];
      float2 b = src[idx + 2048];
      float ang = sign * (6.28318530717958647692f / 4096.0f) * (float)sp;
      float sn, cs;
      __sincosf(ang, &sn, &cs);
      float2 sum = make_float2(a.x + b.x, a.y + b.y);
      float2 dif = make_float2(a.x - b.x, a.y - b.y);
      float2 tw  = make_float2(dif.x * cs - dif.y * sn, dif.x * sn + dif.y * cs);
      const int o = idx + sp;
      dst[o] = sum;
      dst[o + s] = tw;
    }
    float2* t = src; src = dst; dst = t;
  }
  __syncthreads();
}

// ---------------------------------------------------------------------------
// qk_cross: z = q + i*k, FFT, Re(conj(Q)K) = 0.25*Im(conj(Zf+Zc)(Zf-Zc)).
// qkT: [2048][16384]; rows 0..1023 = q, rows 1024..2047 = k.
// ---------------------------------------------------------------------------
__global__ __launch_bounds__(256)
void qk_cross_kernel(const float* __restrict__ qkT, float* __restrict__ attn_raw) {
  __shared__ float2 bufA[4096];
  __shared__ float2 bufB[4096];
  const int tid = threadIdx.x;
  const int blk = blockIdx.x;
  const int d = blk & 63;
  const int bh = blk >> 6;
  const int h = bh & 15;
  const int b = bh >> 4;

  const float* qrow = qkT + (size_t)(h * DHn + d) * NTOT + b * Tsz;
  const float* krow = qkT + (size_t)(Csz + h * DHn + d) * NTOT + b * Tsz;

  for (int t = tid; t < 4096; t += 256)
    bufA[t] = make_float2(qrow[t], krow[t]);

  fft4096(bufA, bufB, tid, -1.0f);

  float* outp = attn_raw + (size_t)bh * Fn;
  for (int f = tid; f < Fn; f += 256) {
    float2 zf = bufA[f];
    float2 zn = bufA[(4096 - f) & 4095];
    float ar = zf.x + zn.x;
    float ai = zf.y - zn.y;
    float br = zf.x - zn.x;
    float bi = zf.y + zn.y;
    float val = 0.03125f * (ar * bi - ai * br);
    atomicAdd(&outp[f], val);
  }
}

// ---------------------------------------------------------------------------
__global__ __launch_bounds__(256)
void softmax_kernel(const float* __restrict__ raw, float* __restrict__ attn) {
  __shared__ float red[256];
  const int tid = threadIdx.x;
  const float* in = raw + (size_t)blockIdx.x * Fn;
  float* outp = attn + (size_t)blockIdx.x * Fn;

  float lmax = -3.4e38f;
  for (int f = tid; f < Fn; f += 256) lmax = fmaxf(lmax, in[f]);
  red[tid] = lmax;
  __syncthreads();
  for (int off = 128; off > 0; off >>= 1) {
    if (tid < off) red[tid] = fmaxf(red[tid], red[tid + off]);
    __syncthreads();
  }
  const float mx = red[0];
  __syncthreads();

  float lsum = 0.f;
  for (int f = tid; f < Fn; f += 256) lsum += __expf(in[f] - mx);
  red[tid] = lsum;
  __syncthreads();
  for (int off = 128; off > 0; off >>= 1) {
    if (tid < off) red[tid] += red[tid + off];
    __syncthreads();
  }
  const float inv = 1.0f / red[0];
  for (int f = tid; f < Fn; f += 256) outp[f] = __expf(in[f] - mx) * inv;
}

// ---------------------------------------------------------------------------
// v_filter: z = v[d0] + i*v[d1]; FFT; multiply by real symmetric filter a[f];
// IFFT; write y0,y1 to vbarT.
// ---------------------------------------------------------------------------
__global__ __launch_bounds__(256)
void v_filter_kernel(const float* __restrict__ vT, float* __restrict__ vbarT,
                     const float* __restrict__ attn) {
  __shared__ float2 bufA[4096];
  __shared__ float2 bufB[4096];
  const int tid = threadIdx.x;
  const int blk = blockIdx.x;
  const int jp = blk & 31;
  const int bh = blk >> 5;
  const int h = bh & 15;
  const int b = bh >> 4;
  const int d0 = jp * 2;

  const float* v0 = vT + (size_t)(h * DHn + d0) * NTOT + b * Tsz;
  const float* v1 = v0 + NTOT;

  for (int t = tid; t < 4096; t += 256)
    bufA[t] = make_float2(v0[t], v1[t]);

  fft4096(bufA, bufB, tid, -1.0f);

  const float* a = attn + (size_t)bh * Fn;
  for (int f = tid; f < 4096; f += 256) {
    int fm = (f <= 2048) ? f : (4096 - f);
    float s = a[fm];
    float2 z = bufA[f];
    bufA[f] = make_float2(z.x * s, z.y * s);
  }

  fft4096(bufA, bufB, tid, +1.0f);

  float* y0 = vbarT + (size_t)(h * DHn + d0) * NTOT + b * Tsz;
  float* y1 = y0 + NTOT;
  const float inv = 1.0f / 4096.0f;
  for (int t = tid; t < 4096; t += 256) {
    float2 z = bufA[t];
    y0[t] = z.x * inv;
    y1[t] = z.y * inv;
  }
}

__global__ void zero_kernel(float* __restrict__ p, int n) {
  int i = blockIdx.x * blockDim.x + threadIdx.x;
  if (i < n) p[i] = 0.f;
}

// ---------------------------------------------------------------------------
// Workspace layout (peak 168,821,248 B; round 1 proved >= 202 MB exists):
//   [0,           134217728)  R1: phases A/B = qkT [2048][16384] f32
//                             phase C: vT [1024][16384] (q-half)
//                             phase D: vbarT [1024][16384] (k-half)
//                             phase E: VThi/VTlo [16384][1024] bf16 (q-half)
//   [134217728,  134742272)   attn_raw [64][2049] f32
//   [134742272,  135266816)   attn     [64][2049] f32
//   [135266816,  141558272)   Whi [3072][1024] bf16
//   [141558272,  147849728)   Wlo
//   [147849728,  156238336)   Xhi panel [4096][1024] bf16 (reused 8x)
//   [156238336,  164626944)   Xlo panel
//   [164626944,  166724096)   Wouthi [1024][1024] bf16
//   [166724096,  168821248)   Woutlo
// ---------------------------------------------------------------------------
extern "C" void kernel_launch(void* const* d_in, const int* in_sizes, int n_in,
                              void* d_out, int out_size, void* d_ws, size_t ws_size,
                              hipStream_t stream) {
  const float* x    = (const float*)d_in[0];   // [4,4096,1024]
  const float* Wqkv = (const float*)d_in[1];   // [3072,1024]
  const float* Wout = (const float*)d_in[2];   // [1024,1024]
  const float* bout = (const float*)d_in[3];   // [1024]
  float* out = (float*)d_out;                  // [16384,1024]

  char* ws = (char*)d_ws;
  float* qkT      = (float*)ws;
  float* vT       = (float*)ws;
  __bf16* VThi    = (__bf16*)ws;                              // phase E (q-half)
  __bf16* VTlo    = (__bf16*)(ws + 33554432ull);
  float* vbarT    = (float*)(ws + 67108864ull);
  float* attn_raw = (float*)(ws + 134217728ull);
  float* attn     = (float*)(ws + 134742272ull);
  __bf16* Whi     = (__bf16*)(ws + 135266816ull);
  __bf16* Wlo     = (__bf16*)(ws + 141558272ull);
  __bf16* Xhi     = (__bf16*)(ws + 147849728ull);
  __bf16* Xlo     = (__bf16*)(ws + 156238336ull);
  __bf16* Wouthi  = (__bf16*)(ws + 164626944ull);
  __bf16* Woutlo  = (__bf16*)(ws + 166724096ull);

  const int nraw = BHn * Fn;
  zero_kernel<<<(nraw + 255) / 256, 256, 0, stream>>>(attn_raw, nraw);

  // W_qkv -> hi/lo (all 3072 rows); W_out -> hi/lo
  cvt_hilo_kernel<<<3072, 256, 0, stream>>>((const float4*)Wqkv,
                                            (bf16x4*)Whi, (bf16x4*)Wlo, 786432);
  cvt_hilo_kernel<<<1024, 256, 0, stream>>>((const float4*)Wout,
                                            (bf16x4*)Wouthi, (bf16x4*)Woutlo, 262144);

  // Phase A: q,k rows (2048) x all columns, panel by panel
  for (int p = 0; p < 4; ++p) {
    cvt_hilo_kernel<<<4096, 256, 0, stream>>>((const float4*)(x + (size_t)p * 4194304),
                                              (bf16x4*)Xhi, (bf16x4*)Xlo, 1048576);
    gemm_mfma_split<<<dim3(32, 16), 256, 0, stream>>>(Whi, Wlo, Xhi, Xlo, qkT, p * 4096);
  }

  qk_cross_kernel<<<Bsz * Hn * DHn, 256, 0, stream>>>(qkT, attn_raw);
  softmax_kernel<<<BHn, 256, 0, stream>>>(attn_raw, attn);

  // Phase C: v rows (1024) — q,k dead; vT overwrites q-half of R1
  for (int p = 0; p < 4; ++p) {
    cvt_hilo_kernel<<<4096, 256, 0, stream>>>((const float4*)(x + (size_t)p * 4194304),
                                              (bf16x4*)Xhi, (bf16x4*)Xlo, 1048576);
    gemm_mfma_split<<<dim3(32, 8), 256, 0, stream>>>(Whi + 2048 * Csz, Wlo + 2048 * Csz,
                                                     Xhi, Xlo, vT, p * 4096);
  }

  // Phase D: spectral filter v -> vbar (k-half)
  v_filter_kernel<<<Bsz * Hn * (DHn / 2), 256, 0, stream>>>(vT, vbarT, attn);

  // Phase E: vbarT [c][n] f32 -> VT hi/lo [n][c] bf16 (vT region is dead)
  transpose_cvt_kernel<<<dim3(NTOT / 64, Csz / 64), 256, 0, stream>>>(vbarT, VThi, VTlo);

  // Phase F: out = VT x Wout^T + bias (MFMA split)
  gemm2_mfma<<<dim3(Csz / 128, NTOT / 128), 256, 0, stream>>>(VThi, VTlo,
                                                              Wouthi, Woutlo, bout, out);
}

// Round 5
// 838.494 us; speedup vs baseline: 2.1413x; 1.0838x over previous
//
#include <hip/hip_runtime.h>
#include <math.h>

// Problem constants
#define Bsz   4
#define Tsz   4096
#define Csz   1024
#define Hn    16
#define DHn   64
#define NTOT  (Bsz * Tsz)      // 16384 rows of x
#define M3    (3 * Csz)        // 3072
#define Fn    2049             // T/2 + 1
#define BHn   (Bsz * Hn)       // 64
#define HALFN 8192             // 2 batches of columns

typedef __bf16 bf16x8 __attribute__((ext_vector_type(8)));
typedef __bf16 bf16x4 __attribute__((ext_vector_type(4)));
typedef float  f32x4  __attribute__((ext_vector_type(4)));

// ---------------------------------------------------------------------------
// async global->LDS, 16B per lane. gptr per-lane; lptr wave-uniform
// (HW writes lptr + lane*16).
// ---------------------------------------------------------------------------
__device__ __forceinline__ void gload_lds16(const void* g, void* l) {
  __builtin_amdgcn_global_load_lds(
      (const __attribute__((address_space(1))) void*)g,
      (__attribute__((address_space(3))) void*)l, 16, 0, 0);
}

// ---------------------------------------------------------------------------
// XCD-aware bijective block swizzle (T1). Requires gridDim.x*y % 8 == 0
// (all our GEMM grids are). XCD k then owns a contiguous chunk of the
// x-fastest block space -> A-tile reuse is L2-local per XCD.
// ---------------------------------------------------------------------------
__device__ __forceinline__ void xcd_swizzle(int& bx, int& by) {
  const int gx = gridDim.x, gy = gridDim.y;
  const int nwg = gx * gy;
  if ((nwg & 7) == 0) {
    const int flat = by * gx + bx;
    const int q = nwg >> 3;
    const int nf = (flat & 7) * q + (flat >> 3);
    bx = nf % gx;
    by = nf / gx;
  }
}

// ---------------------------------------------------------------------------
// f32 -> (hi, lo) bf16 split, 4 elems/thread. hi = RNE(v), lo = RNE(v - hi).
// ---------------------------------------------------------------------------
__global__ __launch_bounds__(256)
void cvt_hilo_kernel(const float4* __restrict__ in, bf16x4* __restrict__ hi,
                     bf16x4* __restrict__ lo, int n4) {
  int i = blockIdx.x * blockDim.x + threadIdx.x;
  if (i >= n4) return;
  float4 v = in[i];
  bf16x4 h, l;
  h[0] = (__bf16)v.x; h[1] = (__bf16)v.y; h[2] = (__bf16)v.z; h[3] = (__bf16)v.w;
  l[0] = (__bf16)(v.x - (float)h[0]);
  l[1] = (__bf16)(v.y - (float)h[1]);
  l[2] = (__bf16)(v.z - (float)h[2]);
  l[3] = (__bf16)(v.w - (float)h[3]);
  hi[i] = h;
  lo[i] = l;
}

// ---------------------------------------------------------------------------
// Transpose + hi/lo convert: src [1024][16384] f32 -> hi/lo [16384][1024] bf16.
// 64x64 tiles via LDS; padded [64][65] keeps banks 2-way (free on CDNA4).
// ---------------------------------------------------------------------------
__global__ __launch_bounds__(256)
void transpose_cvt_kernel(const float* __restrict__ src,
                          __bf16* __restrict__ hi, __bf16* __restrict__ lo) {
  __shared__ float tile[64][65];
  const int tid = threadIdx.x;
  const int n0 = blockIdx.x * 64;
  const int c0 = blockIdx.y * 64;
  const int col = tid & 63;
  const int row4 = tid >> 6;   // 0..3, constant per wave
#pragma unroll
  for (int i = 0; i < 16; ++i) {
    const int r = i * 4 + row4;
    tile[r][col] = src[(size_t)(c0 + r) * NTOT + n0 + col];
  }
  __syncthreads();
#pragma unroll
  for (int i = 0; i < 16; ++i) {
    const int n = i * 4 + row4;
    const float v = tile[col][n];
    const __bf16 h = (__bf16)v;
    const __bf16 l = (__bf16)(v - (float)h);
    hi[(size_t)(n0 + n) * Csz + c0 + col] = h;
    lo[(size_t)(n0 + n) * Csz + c0 + col] = l;
  }
}

// ---------------------------------------------------------------------------
// Split-bf16 MFMA GEMM: C[m][nbase+n] = sum_k A[m][k] * B[n][k]
//   A ~ (Ahi+Alo), B ~ (Bhi+Blo); product = AhBh + AhBl + AlBh.
// 128x128 tile, 4 waves (2x2), each wave 64x64 = 4x4 frags of 16x16x32.
// LDS per k-step (BK=32): 4 tiles of 128rows x 32bf16 = 8KB each; layout
// [rowblock(8)][kchunk(4)][row16(16)] x 16B so the global_load_lds lane-linear
// write order == the fragment ds_read_b128 order (no repack, no conflicts).
// B rows are panel-local (HALFN rows); C row stride = NTOT.
// ---------------------------------------------------------------------------
__global__ __launch_bounds__(256)
void gemm_mfma_split(const __bf16* __restrict__ Ahi, const __bf16* __restrict__ Alo,
                     const __bf16* __restrict__ Bhi, const __bf16* __restrict__ Blo,
                     float* __restrict__ C, int nbase) {
  __shared__ char lds[32768];
  char* ldsAh = lds;
  char* ldsAl = lds + 8192;
  char* ldsBh = lds + 16384;
  char* ldsBl = lds + 24576;

  int bxi = blockIdx.x, byi = blockIdx.y;
  xcd_swizzle(bxi, byi);

  const int tid  = threadIdx.x;
  const int wid  = tid >> 6;
  const int lane = tid & 63;
  const int wm = wid >> 1, wn = wid & 1;
  const int m0 = byi * 128;
  const int n0 = bxi * 128;

  const int r16 = lane & 15;
  const int kc  = lane >> 4;

  const int aR0 = m0 + wid * 16 + r16;
  const int bR0 = n0 + wid * 16 + r16;
  const __bf16* pAh0 = Ahi + (size_t)aR0 * Csz + kc * 8;
  const __bf16* pAh1 = pAh0 + (size_t)64 * Csz;
  const __bf16* pAl0 = Alo + (size_t)aR0 * Csz + kc * 8;
  const __bf16* pAl1 = pAl0 + (size_t)64 * Csz;
  const __bf16* pBh0 = Bhi + (size_t)bR0 * Csz + kc * 8;
  const __bf16* pBh1 = pBh0 + (size_t)64 * Csz;
  const __bf16* pBl0 = Blo + (size_t)bR0 * Csz + kc * 8;
  const __bf16* pBl1 = pBl0 + (size_t)64 * Csz;

  char* dAh0 = ldsAh + wid * 1024;  char* dAh1 = dAh0 + 4096;
  char* dAl0 = ldsAl + wid * 1024;  char* dAl1 = dAl0 + 4096;
  char* dBh0 = ldsBh + wid * 1024;  char* dBh1 = dBh0 + 4096;
  char* dBl0 = ldsBl + wid * 1024;  char* dBl1 = dBl0 + 4096;

  f32x4 acc[4][4];
#pragma unroll
  for (int i = 0; i < 4; ++i)
#pragma unroll
    for (int j = 0; j < 4; ++j) acc[i][j] = (f32x4)(0.f);

  for (int k0 = 0; k0 < Csz; k0 += 32) {
    __syncthreads();
    gload_lds16(pAh0 + k0, dAh0);
    gload_lds16(pAh1 + k0, dAh1);
    gload_lds16(pAl0 + k0, dAl0);
    gload_lds16(pAl1 + k0, dAl1);
    gload_lds16(pBh0 + k0, dBh0);
    gload_lds16(pBh1 + k0, dBh1);
    gload_lds16(pBl0 + k0, dBl0);
    gload_lds16(pBl1 + k0, dBl1);
    __syncthreads();

    bf16x8 ah[4], al[4], bh[4], bl[4];
#pragma unroll
    for (int f = 0; f < 4; ++f) {
      const int offA = (wm * 4 + f) * 1024 + lane * 16;
      ah[f] = *(const bf16x8*)(ldsAh + offA);
      al[f] = *(const bf16x8*)(ldsAl + offA);
      const int offB = (wn * 4 + f) * 1024 + lane * 16;
      bh[f] = *(const bf16x8*)(ldsBh + offB);
      bl[f] = *(const bf16x8*)(ldsBl + offB);
    }
#pragma unroll
    for (int fm = 0; fm < 4; ++fm)
#pragma unroll
      for (int fn = 0; fn < 4; ++fn) {
        acc[fm][fn] = __builtin_amdgcn_mfma_f32_16x16x32_bf16(ah[fm], bh[fn], acc[fm][fn], 0, 0, 0);
        acc[fm][fn] = __builtin_amdgcn_mfma_f32_16x16x32_bf16(ah[fm], bl[fn], acc[fm][fn], 0, 0, 0);
        acc[fm][fn] = __builtin_amdgcn_mfma_f32_16x16x32_bf16(al[fm], bh[fn], acc[fm][fn], 0, 0, 0);
      }
  }

  const int cm = m0 + wm * 64 + (lane >> 4) * 4;
  const int cn = nbase + n0 + wn * 64 + (lane & 15);
#pragma unroll
  for (int fm = 0; fm < 4; ++fm)
#pragma unroll
    for (int r = 0; r < 4; ++r) {
      float* cp = C + (size_t)(cm + fm * 16 + r) * NTOT + cn;
#pragma unroll
      for (int fn = 0; fn < 4; ++fn) cp[fn * 16] = acc[fm][fn][r];
    }
}

// ---------------------------------------------------------------------------
// gemm2_mfma: out[m][j] = sum_c A[m][c]*B[j][c] + bias[j], row stride Csz.
// A = VT hi/lo [16384][1024], B = Wout hi/lo [1024][1024].
// ---------------------------------------------------------------------------
__global__ __launch_bounds__(256)
void gemm2_mfma(const __bf16* __restrict__ Ahi, const __bf16* __restrict__ Alo,
                const __bf16* __restrict__ Bhi, const __bf16* __restrict__ Blo,
                const float* __restrict__ bias, float* __restrict__ C) {
  __shared__ char lds[32768];
  char* ldsAh = lds;
  char* ldsAl = lds + 8192;
  char* ldsBh = lds + 16384;
  char* ldsBl = lds + 24576;

  int bxi = blockIdx.x, byi = blockIdx.y;
  xcd_swizzle(bxi, byi);

  const int tid  = threadIdx.x;
  const int wid  = tid >> 6;
  const int lane = tid & 63;
  const int wm = wid >> 1, wn = wid & 1;
  const int m0 = byi * 128;
  const int n0 = bxi * 128;

  const int r16 = lane & 15;
  const int kc  = lane >> 4;

  const int aR0 = m0 + wid * 16 + r16;
  const int bR0 = n0 + wid * 16 + r16;
  const __bf16* pAh0 = Ahi + (size_t)aR0 * Csz + kc * 8;
  const __bf16* pAh1 = pAh0 + (size_t)64 * Csz;
  const __bf16* pAl0 = Alo + (size_t)aR0 * Csz + kc * 8;
  const __bf16* pAl1 = pAl0 + (size_t)64 * Csz;
  const __bf16* pBh0 = Bhi + (size_t)bR0 * Csz + kc * 8;
  const __bf16* pBh1 = pBh0 + (size_t)64 * Csz;
  const __bf16* pBl0 = Blo + (size_t)bR0 * Csz + kc * 8;
  const __bf16* pBl1 = pBl0 + (size_t)64 * Csz;

  char* dAh0 = ldsAh + wid * 1024;  char* dAh1 = dAh0 + 4096;
  char* dAl0 = ldsAl + wid * 1024;  char* dAl1 = dAl0 + 4096;
  char* dBh0 = ldsBh + wid * 1024;  char* dBh1 = dBh0 + 4096;
  char* dBl0 = ldsBl + wid * 1024;  char* dBl1 = dBl0 + 4096;

  f32x4 acc[4][4];
#pragma unroll
  for (int i = 0; i < 4; ++i)
#pragma unroll
    for (int j = 0; j < 4; ++j) acc[i][j] = (f32x4)(0.f);

  for (int k0 = 0; k0 < Csz; k0 += 32) {
    __syncthreads();
    gload_lds16(pAh0 + k0, dAh0);
    gload_lds16(pAh1 + k0, dAh1);
    gload_lds16(pAl0 + k0, dAl0);
    gload_lds16(pAl1 + k0, dAl1);
    gload_lds16(pBh0 + k0, dBh0);
    gload_lds16(pBh1 + k0, dBh1);
    gload_lds16(pBl0 + k0, dBl0);
    gload_lds16(pBl1 + k0, dBl1);
    __syncthreads();

    bf16x8 ah[4], al[4], bh[4], bl[4];
#pragma unroll
    for (int f = 0; f < 4; ++f) {
      const int offA = (wm * 4 + f) * 1024 + lane * 16;
      ah[f] = *(const bf16x8*)(ldsAh + offA);
      al[f] = *(const bf16x8*)(ldsAl + offA);
      const int offB = (wn * 4 + f) * 1024 + lane * 16;
      bh[f] = *(const bf16x8*)(ldsBh + offB);
      bl[f] = *(const bf16x8*)(ldsBl + offB);
    }
#pragma unroll
    for (int fm = 0; fm < 4; ++fm)
#pragma unroll
      for (int fn = 0; fn < 4; ++fn) {
        acc[fm][fn] = __builtin_amdgcn_mfma_f32_16x16x32_bf16(ah[fm], bh[fn], acc[fm][fn], 0, 0, 0);
        acc[fm][fn] = __builtin_amdgcn_mfma_f32_16x16x32_bf16(ah[fm], bl[fn], acc[fm][fn], 0, 0, 0);
        acc[fm][fn] = __builtin_amdgcn_mfma_f32_16x16x32_bf16(al[fm], bh[fn], acc[fm][fn], 0, 0, 0);
      }
  }

  const int cm = m0 + wm * 64 + (lane >> 4) * 4;
  const int cn = n0 + wn * 64 + (lane & 15);
  float bb[4];
#pragma unroll
  for (int fn = 0; fn < 4; ++fn) bb[fn] = bias[cn + fn * 16];
#pragma unroll
  for (int fm = 0; fm < 4; ++fm)
#pragma unroll
    for (int r = 0; r < 4; ++r) {
      float* cp = C + (size_t)(cm + fm * 16 + r) * Csz + cn;
#pragma unroll
      for (int fn = 0; fn < 4; ++fn) cp[fn * 16] = acc[fm][fn][r] + bb[fn];
    }
}

// ---------------------------------------------------------------------------
// 4096-point complex Stockham FFT in LDS (radix-2, 12 stages, autosort).
// ---------------------------------------------------------------------------
__device__ __forceinline__ void fft4096(float2* X, float2* Y, int tid, float sign) {
  float2* src = X;
  float2* dst = Y;
#pragma unroll 1
  for (int stage = 0; stage < 12; ++stage) {
    const int s = 1 << stage;
    __syncthreads();
#pragma unroll
    for (int it = 0; it < 8; ++it) {
      const int idx = tid + (it << 8);
      const int sp = idx & ~(s - 1);
      float2 a = src[idx];
      float2 b = src[idx + 2048];
      float ang = sign * (6.28318530717958647692f / 4096.0f) * (float)sp;
      float sn, cs;
      __sincosf(ang, &sn, &cs);
      float2 sum = make_float2(a.x + b.x, a.y + b.y);
      float2 dif = make_float2(a.x - b.x, a.y - b.y);
      float2 tw  = make_float2(dif.x * cs - dif.y * sn, dif.x * sn + dif.y * cs);
      const int o = idx + sp;
      dst[o] = sum;
      dst[o + s] = tw;
    }
    float2* t = src; src = dst; dst = t;
  }
  __syncthreads();
}

// ---------------------------------------------------------------------------
// qk_cross: z = q + i*k, FFT, Re(conj(Q)K) = 0.25*Im(conj(Zf+Zc)(Zf-Zc)).
// qkT: [2048][16384]; rows 0..1023 = q, rows 1024..2047 = k.
// Launched per 2-batch half: blocks cover bh in [bhbase, bhbase+32).
// ---------------------------------------------------------------------------
__global__ __launch_bounds__(256)
void qk_cross_kernel(const float* __restrict__ qkT, float* __restrict__ attn_raw,
                     int bhbase) {
  __shared__ float2 bufA[4096];
  __shared__ float2 bufB[4096];
  const int tid = threadIdx.x;
  const int blk = blockIdx.x;
  const int d = blk & 63;
  const int bh = bhbase + (blk >> 6);
  const int h = bh & 15;
  const int b = bh >> 4;

  const float* qrow = qkT + (size_t)(h * DHn + d) * NTOT + b * Tsz;
  const float* krow = qkT + (size_t)(Csz + h * DHn + d) * NTOT + b * Tsz;

  for (int t = tid; t < 4096; t += 256)
    bufA[t] = make_float2(qrow[t], krow[t]);

  fft4096(bufA, bufB, tid, -1.0f);

  float* outp = attn_raw + (size_t)bh * Fn;
  for (int f = tid; f < Fn; f += 256) {
    float2 zf = bufA[f];
    float2 zn = bufA[(4096 - f) & 4095];
    float ar = zf.x + zn.x;
    float ai = zf.y - zn.y;
    float br = zf.x - zn.x;
    float bi = zf.y + zn.y;
    float val = 0.03125f * (ar * bi - ai * br);
    atomicAdd(&outp[f], val);
  }
}

// ---------------------------------------------------------------------------
__global__ __launch_bounds__(256)
void softmax_kernel(const float* __restrict__ raw, float* __restrict__ attn) {
  __shared__ float red[256];
  const int tid = threadIdx.x;
  const float* in = raw + (size_t)blockIdx.x * Fn;
  float* outp = attn + (size_t)blockIdx.x * Fn;

  float lmax = -3.4e38f;
  for (int f = tid; f < Fn; f += 256) lmax = fmaxf(lmax, in[f]);
  red[tid] = lmax;
  __syncthreads();
  for (int off = 128; off > 0; off >>= 1) {
    if (tid < off) red[tid] = fmaxf(red[tid], red[tid + off]);
    __syncthreads();
  }
  const float mx = red[0];
  __syncthreads();

  float lsum = 0.f;
  for (int f = tid; f < Fn; f += 256) lsum += __expf(in[f] - mx);
  red[tid] = lsum;
  __syncthreads();
  for (int off = 128; off > 0; off >>= 1) {
    if (tid < off) red[tid] += red[tid + off];
    __syncthreads();
  }
  const float inv = 1.0f / red[0];
  for (int f = tid; f < Fn; f += 256) outp[f] = __expf(in[f] - mx) * inv;
}

// ---------------------------------------------------------------------------
// v_filter: z = v[d0] + i*v[d1]; FFT; multiply by real symmetric filter a[f];
// IFFT; write y0,y1 to vbarT. Launched per 2-batch half.
// ---------------------------------------------------------------------------
__global__ __launch_bounds__(256)
void v_filter_kernel(const float* __restrict__ vT, float* __restrict__ vbarT,
                     const float* __restrict__ attn, int bhbase) {
  __shared__ float2 bufA[4096];
  __shared__ float2 bufB[4096];
  const int tid = threadIdx.x;
  const int blk = blockIdx.x;
  const int jp = blk & 31;
  const int bh = bhbase + (blk >> 5);
  const int h = bh & 15;
  const int b = bh >> 4;
  const int d0 = jp * 2;

  const float* v0 = vT + (size_t)(h * DHn + d0) * NTOT + b * Tsz;
  const float* v1 = v0 + NTOT;

  for (int t = tid; t < 4096; t += 256)
    bufA[t] = make_float2(v0[t], v1[t]);

  fft4096(bufA, bufB, tid, -1.0f);

  const float* a = attn + (size_t)bh * Fn;
  for (int f = tid; f < 4096; f += 256) {
    int fm = (f <= 2048) ? f : (4096 - f);
    float s = a[fm];
    float2 z = bufA[f];
    bufA[f] = make_float2(z.x * s, z.y * s);
  }

  fft4096(bufA, bufB, tid, +1.0f);

  float* y0 = vbarT + (size_t)(h * DHn + d0) * NTOT + b * Tsz;
  float* y1 = y0 + NTOT;
  const float inv = 1.0f / 4096.0f;
  for (int t = tid; t < 4096; t += 256) {
    float2 z = bufA[t];
    y0[t] = z.x * inv;
    y1[t] = z.y * inv;
  }
}

__global__ void zero_kernel(float* __restrict__ p, int n) {
  int i = blockIdx.x * blockDim.x + threadIdx.x;
  if (i < n) p[i] = 0.f;
}

// ---------------------------------------------------------------------------
// Workspace layout (peak 185,598,464 B <= 202.9 MB proven by round 1):
//   [0,           134217728)  R1: qkT [2048][16384] f32 (rows 0..1023 q,
//                             1024..2047 k). Later: vT [1024][16384] in
//                             q-half; vbarT [1024][16384] in k-half;
//                             finally VThi/VTlo [16384][1024] bf16 in q-half.
//   [134217728,  134742272)   attn_raw [64][2049] f32
//   [134742272,  135266816)   attn     [64][2049] f32
//   [135266816,  141558272)   Whi [3072][1024] bf16
//   [141558272,  147849728)   Wlo
//   [147849728,  164626944)   Xhi half [8192][1024] bf16 (2 batches, reused)
//   [164626944,  181404160)   Xlo half
//   [181404160,  183501312)   Wouthi [1024][1024] bf16
//   [183501312,  185598464)   Woutlo
// ---------------------------------------------------------------------------
extern "C" void kernel_launch(void* const* d_in, const int* in_sizes, int n_in,
                              void* d_out, int out_size, void* d_ws, size_t ws_size,
                              hipStream_t stream) {
  const float* x    = (const float*)d_in[0];   // [4,4096,1024]
  const float* Wqkv = (const float*)d_in[1];   // [3072,1024]
  const float* Wout = (const float*)d_in[2];   // [1024,1024]
  const float* bout = (const float*)d_in[3];   // [1024]
  float* out = (float*)d_out;                  // [16384,1024]

  char* ws = (char*)d_ws;
  float* qkT      = (float*)ws;
  float* vT       = (float*)ws;                               // q-half reuse
  __bf16* VThi    = (__bf16*)ws;                              // final reuse
  __bf16* VTlo    = (__bf16*)(ws + 33554432ull);
  float* vbarT    = (float*)(ws + 67108864ull);               // k-half reuse
  float* attn_raw = (float*)(ws + 134217728ull);
  float* attn     = (float*)(ws + 134742272ull);
  __bf16* Whi     = (__bf16*)(ws + 135266816ull);
  __bf16* Wlo     = (__bf16*)(ws + 141558272ull);
  __bf16* Xhi     = (__bf16*)(ws + 147849728ull);
  __bf16* Xlo     = (__bf16*)(ws + 164626944ull);
  __bf16* Wouthi  = (__bf16*)(ws + 181404160ull);
  __bf16* Woutlo  = (__bf16*)(ws + 183501312ull);

  const int nraw = BHn * Fn;
  zero_kernel<<<(nraw + 255) / 256, 256, 0, stream>>>(attn_raw, nraw);

  // Weights -> hi/lo
  cvt_hilo_kernel<<<3072, 256, 0, stream>>>((const float4*)Wqkv,
                                            (bf16x4*)Whi, (bf16x4*)Wlo, 786432);
  cvt_hilo_kernel<<<1024, 256, 0, stream>>>((const float4*)Wout,
                                            (bf16x4*)Wouthi, (bf16x4*)Woutlo, 262144);

  // Per 2-batch half: convert X, q/k GEMM, qk FFT cross-spectrum
  for (int half = 0; half < 2; ++half) {
    cvt_hilo_kernel<<<8192, 256, 0, stream>>>(
        (const float4*)(x + (size_t)half * HALFN * Csz),
        (bf16x4*)Xhi, (bf16x4*)Xlo, 2097152);
    gemm_mfma_split<<<dim3(64, 16), 256, 0, stream>>>(Whi, Wlo, Xhi, Xlo,
                                                      qkT, half * HALFN);
    qk_cross_kernel<<<2048, 256, 0, stream>>>(qkT, attn_raw, half * 32);
  }

  softmax_kernel<<<BHn, 256, 0, stream>>>(attn_raw, attn);

  // v GEMM + spectral filter: half1 first (X half1 still resident), then half0
  gemm_mfma_split<<<dim3(64, 8), 256, 0, stream>>>(Whi + 2048 * Csz, Wlo + 2048 * Csz,
                                                   Xhi, Xlo, vT, 1 * HALFN);
  v_filter_kernel<<<1024, 256, 0, stream>>>(vT, vbarT, attn, 1 * 32);

  cvt_hilo_kernel<<<8192, 256, 0, stream>>>((const float4*)x,
                                            (bf16x4*)Xhi, (bf16x4*)Xlo, 2097152);
  gemm_mfma_split<<<dim3(64, 8), 256, 0, stream>>>(Whi + 2048 * Csz, Wlo + 2048 * Csz,
                                                   Xhi, Xlo, vT, 0);
  v_filter_kernel<<<1024, 256, 0, stream>>>(vT, vbarT, attn, 0);

  // vbarT [c][n] f32 -> VT hi/lo [n][c] bf16 (vT region is dead)
  transpose_cvt_kernel<<<dim3(NTOT / 64, Csz / 64), 256, 0, stream>>>(vbarT, VThi, VTlo);

  // out = VT x Wout^T + bias (MFMA split)
  gemm2_mfma<<<dim3(Csz / 128, NTOT / 128), 256, 0, stream>>>(VThi, VTlo,
                                                              Wouthi, Woutlo, bout, out);
}

// Round 6
// 698.420 us; speedup vs baseline: 2.5708x; 1.2006x over previous
//
#include <hip/hip_runtime.h>
#include <math.h>

// Problem constants
#define Bsz   4
#define Tsz   4096
#define Csz   1024
#define Hn    16
#define DHn   64
#define NTOT  (Bsz * Tsz)      // 16384 rows of x
#define M3    (3 * Csz)        // 3072
#define Fn    2049             // T/2 + 1
#define BHn   (Bsz * Hn)       // 64
#define HALFN 8192             // 2 batches of columns

typedef __bf16 bf16x8 __attribute__((ext_vector_type(8)));
typedef __bf16 bf16x4 __attribute__((ext_vector_type(4)));
typedef float  f32x4  __attribute__((ext_vector_type(4)));

// ---------------------------------------------------------------------------
// async global->LDS, 16B per lane. gptr per-lane; lptr wave-uniform
// (HW writes lptr + lane*16).
// ---------------------------------------------------------------------------
__device__ __forceinline__ void gload_lds16(const void* g, void* l) {
  __builtin_amdgcn_global_load_lds(
      (const __attribute__((address_space(1))) void*)g,
      (__attribute__((address_space(3))) void*)l, 16, 0, 0);
}

// ---------------------------------------------------------------------------
// f32 -> (hi, lo) bf16 split, 4 elems/thread. hi = RNE(v), lo = RNE(v - hi).
// ---------------------------------------------------------------------------
__global__ __launch_bounds__(256)
void cvt_hilo_kernel(const float4* __restrict__ in, bf16x4* __restrict__ hi,
                     bf16x4* __restrict__ lo, int n4) {
  int i = blockIdx.x * blockDim.x + threadIdx.x;
  if (i >= n4) return;
  float4 v = in[i];
  bf16x4 h, l;
  h[0] = (__bf16)v.x; h[1] = (__bf16)v.y; h[2] = (__bf16)v.z; h[3] = (__bf16)v.w;
  l[0] = (__bf16)(v.x - (float)h[0]);
  l[1] = (__bf16)(v.y - (float)h[1]);
  l[2] = (__bf16)(v.z - (float)h[2]);
  l[3] = (__bf16)(v.w - (float)h[3]);
  hi[i] = h;
  lo[i] = l;
}

// ---------------------------------------------------------------------------
// Transpose + hi/lo convert: src [1024][16384] f32 -> hi/lo [16384][1024] bf16.
// ---------------------------------------------------------------------------
__global__ __launch_bounds__(256)
void transpose_cvt_kernel(const float* __restrict__ src,
                          __bf16* __restrict__ hi, __bf16* __restrict__ lo) {
  __shared__ float tile[64][65];
  const int tid = threadIdx.x;
  const int n0 = blockIdx.x * 64;
  const int c0 = blockIdx.y * 64;
  const int col = tid & 63;
  const int row4 = tid >> 6;
#pragma unroll
  for (int i = 0; i < 16; ++i) {
    const int r = i * 4 + row4;
    tile[r][col] = src[(size_t)(c0 + r) * NTOT + n0 + col];
  }
  __syncthreads();
#pragma unroll
  for (int i = 0; i < 16; ++i) {
    const int n = i * 4 + row4;
    const float v = tile[col][n];
    const __bf16 h = (__bf16)v;
    const __bf16 l = (__bf16)(v - (float)h);
    hi[(size_t)(n0 + n) * Csz + c0 + col] = h;
    lo[(size_t)(n0 + n) * Csz + c0 + col] = l;
  }
}

// ---------------------------------------------------------------------------
// 8-phase-style split-bf16 MFMA GEMM (T3+T4+T5 port).
//   C[m][nbase+n] = sum_k A[m][k]*B[n][k]  (+ bias[n] if bias != null),
//   A ~ (Ahi+Alo), B ~ (Bhi+Blo); product = AhBh + AhBl + AlBh.
// Tile BM x 256 (BM = 32*MF), 512 threads = 8 waves (2M x 4N); per wave
// MF x 4 frags of 16x16x32. BK=32, double-buffered LDS (2 x (2*SA+2*SB)).
// Staging: lane-linear global_load_lds, [rowblock][kchunk][row16] x 16B so
// DMA write order == ds_read_b128 fragment order (conflict-free, no repack).
// Schedule per K-tile: vmcnt(0); barrier; issue next tile's 8 DMAs; then
// 4 phases {ds_read quadrant; lgkmcnt(0); sched_barrier; setprio(1);
// MFMA x 3*MF; setprio(0); barrier}. A-half regs persist across 2 n-phases.
// ---------------------------------------------------------------------------
template<int MF>
__global__ __launch_bounds__(512, 2)
void gemm_8p(const __bf16* __restrict__ Ahi, const __bf16* __restrict__ Alo,
             const __bf16* __restrict__ Bhi, const __bf16* __restrict__ Blo,
             float* __restrict__ C, int ldC, int nbase,
             const float* __restrict__ bias, int colmap) {
  constexpr int BM  = 32 * MF;
  constexpr int SA  = BM * 64;           // bytes per A tile (BM rows x 32 bf16)
  constexpr int SB  = 16384;             // 256 rows x 32 bf16 x 2B
  constexpr int BUF = 2 * SA + 2 * SB;
  __shared__ __align__(16) char lds[2 * BUF];

  const int tid  = threadIdx.x;
  const int wid  = tid >> 6;             // 0..7
  const int lane = tid & 63;
  const int wm = wid >> 2, wn = wid & 3; // 2 x 4 wave grid

  // XCD-aware swizzle: colmap=1 -> each XCD owns a bx-band (B L2-resident);
  // colmap=0 -> by-band (B small, A banded).
  int bx = blockIdx.x, by = blockIdx.y;
  {
    const int gx = gridDim.x, gy = gridDim.y;
    const int nwg = gx * gy;
    if ((nwg & 7) == 0) {
      const int flat  = by * gx + bx;
      const int chunk = nwg >> 3;
      const int nf    = (flat & 7) * chunk + (flat >> 3);
      if (colmap) { bx = nf / gy; by = nf % gy; }
      else        { bx = nf % gx; by = nf / gx; }
    }
  }
  const int m0 = by * BM;
  const int n0 = bx * 256;

  const int r16 = lane & 15;             // row within 16-row block
  const int kc  = lane >> 4;             // k-chunk (8 bf16)

  // global staging pointers (per-lane); wave stages rowblock wid (+8 for MF=8)
  const __bf16* gAh0 = Ahi + (size_t)(m0 + wid * 16 + r16) * Csz + kc * 8;
  const __bf16* gAl0 = Alo + (size_t)(m0 + wid * 16 + r16) * Csz + kc * 8;
  const __bf16* gBh0 = Bhi + (size_t)(n0 + wid * 16 + r16) * Csz + kc * 8;
  const __bf16* gBl0 = Blo + (size_t)(n0 + wid * 16 + r16) * Csz + kc * 8;
  const __bf16* gAh1 = gAh0 + (size_t)128 * Csz;   // used only if MF==8
  const __bf16* gAl1 = gAl0 + (size_t)128 * Csz;
  const __bf16* gBh1 = gBh0 + (size_t)128 * Csz;
  const __bf16* gBl1 = gBl0 + (size_t)128 * Csz;
  const int dW = wid * 1024;             // wave-uniform LDS chunk

  f32x4 acc[MF][4];
#pragma unroll
  for (int i = 0; i < MF; ++i)
#pragma unroll
    for (int j = 0; j < 4; ++j) acc[i][j] = (f32x4)(0.f);

  auto stage = [&](char* base, int k0) {
    gload_lds16(gAh0 + k0, base + dW);
    if constexpr (MF == 8) gload_lds16(gAh1 + k0, base + dW + 8192);
    gload_lds16(gAl0 + k0, base + SA + dW);
    if constexpr (MF == 8) gload_lds16(gAl1 + k0, base + SA + dW + 8192);
    gload_lds16(gBh0 + k0, base + 2 * SA + dW);
    gload_lds16(gBh1 + k0, base + 2 * SA + dW + 8192);
    gload_lds16(gBl0 + k0, base + 2 * SA + SB + dW);
    gload_lds16(gBl1 + k0, base + 2 * SA + SB + dW + 8192);
  };

  stage(lds, 0);

  for (int t = 0; t < 32; ++t) {
    char* buf = lds + (t & 1) * BUF;
    asm volatile("s_waitcnt vmcnt(0)" ::: "memory");
    __builtin_amdgcn_s_barrier();
    if (t < 31) stage(lds + ((t & 1) ^ 1) * BUF, (t + 1) * 32);

#pragma unroll
    for (int mh = 0; mh < 2; ++mh) {
      bf16x8 ah[MF / 2], al[MF / 2];
#pragma unroll
      for (int f = 0; f < MF / 2; ++f) {
        const int off = (wm * MF + mh * (MF / 2) + f) * 1024 + lane * 16;
        ah[f] = *(const bf16x8*)(buf + off);
        al[f] = *(const bf16x8*)(buf + SA + off);
      }
#pragma unroll
      for (int nh = 0; nh < 2; ++nh) {
        bf16x8 bh[2], bl[2];
#pragma unroll
        for (int g = 0; g < 2; ++g) {
          const int off = (wn * 4 + nh * 2 + g) * 1024 + lane * 16;
          bh[g] = *(const bf16x8*)(buf + 2 * SA + off);
          bl[g] = *(const bf16x8*)(buf + 2 * SA + SB + off);
        }
        asm volatile("s_waitcnt lgkmcnt(0)" ::: "memory");
        __builtin_amdgcn_sched_barrier(0);
        __builtin_amdgcn_s_setprio(1);
#pragma unroll
        for (int f = 0; f < MF / 2; ++f)
#pragma unroll
          for (int g = 0; g < 2; ++g) {
            f32x4 a_ = acc[mh * (MF / 2) + f][nh * 2 + g];
            a_ = __builtin_amdgcn_mfma_f32_16x16x32_bf16(ah[f], bh[g], a_, 0, 0, 0);
            a_ = __builtin_amdgcn_mfma_f32_16x16x32_bf16(ah[f], bl[g], a_, 0, 0, 0);
            a_ = __builtin_amdgcn_mfma_f32_16x16x32_bf16(al[f], bh[g], a_, 0, 0, 0);
            acc[mh * (MF / 2) + f][nh * 2 + g] = a_;
          }
        __builtin_amdgcn_s_setprio(0);
        __builtin_amdgcn_s_barrier();
      }
    }
  }

  // epilogue: D row=(lane>>4)*4+r, col=lane&15 (m89 layout)
  const int cm = m0 + wm * (MF * 16) + (lane >> 4) * 4;
  const int cn = nbase + n0 + wn * 64 + (lane & 15);
  float bb[4];
#pragma unroll
  for (int g = 0; g < 4; ++g) bb[g] = bias ? bias[cn - nbase + g * 16] : 0.f;
#pragma unroll
  for (int fm = 0; fm < MF; ++fm)
#pragma unroll
    for (int r = 0; r < 4; ++r) {
      float* cp = C + (size_t)(cm + fm * 16 + r) * ldC + cn;
#pragma unroll
      for (int g = 0; g < 4; ++g) cp[g * 16] = acc[fm][g][r] + bb[g];
    }
}

// ---------------------------------------------------------------------------
// 4096-point complex Stockham FFT in LDS (radix-2, 12 stages, autosort).
// ---------------------------------------------------------------------------
__device__ __forceinline__ void fft4096(float2* X, float2* Y, int tid, float sign) {
  float2* src = X;
  float2* dst = Y;
#pragma unroll 1
  for (int stage = 0; stage < 12; ++stage) {
    const int s = 1 << stage;
    __syncthreads();
#pragma unroll
    for (int it = 0; it < 8; ++it) {
      const int idx = tid + (it << 8);
      const int sp = idx & ~(s - 1);
      float2 a = src[idx];
      float2 b = src[idx + 2048];
      float ang = sign * (6.28318530717958647692f / 4096.0f) * (float)sp;
      float sn, cs;
      __sincosf(ang, &sn, &cs);
      float2 sum = make_float2(a.x + b.x, a.y + b.y);
      float2 dif = make_float2(a.x - b.x, a.y - b.y);
      float2 tw  = make_float2(dif.x * cs - dif.y * sn, dif.x * sn + dif.y * cs);
      const int o = idx + sp;
      dst[o] = sum;
      dst[o + s] = tw;
    }
    float2* t = src; src = dst; dst = t;
  }
  __syncthreads();
}

// ---------------------------------------------------------------------------
// qk_cross: z = q + i*k, FFT, Re(conj(Q)K) = 0.25*Im(conj(Zf+Zc)(Zf-Zc)).
// qkT: [2048][16384]; rows 0..1023 = q, rows 1024..2047 = k.
// Per 2-batch half: blocks cover bh in [bhbase, bhbase+32).
// ---------------------------------------------------------------------------
__global__ __launch_bounds__(256)
void qk_cross_kernel(const float* __restrict__ qkT, float* __restrict__ attn_raw,
                     int bhbase) {
  __shared__ float2 bufA[4096];
  __shared__ float2 bufB[4096];
  const int tid = threadIdx.x;
  const int blk = blockIdx.x;
  const int d = blk & 63;
  const int bh = bhbase + (blk >> 6);
  const int h = bh & 15;
  const int b = bh >> 4;

  const float* qrow = qkT + (size_t)(h * DHn + d) * NTOT + b * Tsz;
  const float* krow = qkT + (size_t)(Csz + h * DHn + d) * NTOT + b * Tsz;

  for (int t = tid; t < 4096; t += 256)
    bufA[t] = make_float2(qrow[t], krow[t]);

  fft4096(bufA, bufB, tid, -1.0f);

  float* outp = attn_raw + (size_t)bh * Fn;
  for (int f = tid; f < Fn; f += 256) {
    float2 zf = bufA[f];
    float2 zn = bufA[(4096 - f) & 4095];
    float ar = zf.x + zn.x;
    float ai = zf.y - zn.y;
    float br = zf.x - zn.x;
    float bi = zf.y + zn.y;
    float val = 0.03125f * (ar * bi - ai * br);
    atomicAdd(&outp[f], val);
  }
}

// ---------------------------------------------------------------------------
__global__ __launch_bounds__(256)
void softmax_kernel(const float* __restrict__ raw, float* __restrict__ attn) {
  __shared__ float red[256];
  const int tid = threadIdx.x;
  const float* in = raw + (size_t)blockIdx.x * Fn;
  float* outp = attn + (size_t)blockIdx.x * Fn;

  float lmax = -3.4e38f;
  for (int f = tid; f < Fn; f += 256) lmax = fmaxf(lmax, in[f]);
  red[tid] = lmax;
  __syncthreads();
  for (int off = 128; off > 0; off >>= 1) {
    if (tid < off) red[tid] = fmaxf(red[tid], red[tid + off]);
    __syncthreads();
  }
  const float mx = red[0];
  __syncthreads();

  float lsum = 0.f;
  for (int f = tid; f < Fn; f += 256) lsum += __expf(in[f] - mx);
  red[tid] = lsum;
  __syncthreads();
  for (int off = 128; off > 0; off >>= 1) {
    if (tid < off) red[tid] += red[tid + off];
    __syncthreads();
  }
  const float inv = 1.0f / red[0];
  for (int f = tid; f < Fn; f += 256) outp[f] = __expf(in[f] - mx) * inv;
}

// ---------------------------------------------------------------------------
// v_filter: z = v[d0] + i*v[d1]; FFT; multiply by real symmetric filter a[f];
// IFFT; write y0,y1 to vbarT. Single dispatch, 2048 blocks (all bh).
// ---------------------------------------------------------------------------
__global__ __launch_bounds__(256)
void v_filter_kernel(const float* __restrict__ vT, float* __restrict__ vbarT,
                     const float* __restrict__ attn) {
  __shared__ float2 bufA[4096];
  __shared__ float2 bufB[4096];
  const int tid = threadIdx.x;
  const int blk = blockIdx.x;
  const int jp = blk & 31;
  const int bh = blk >> 5;
  const int h = bh & 15;
  const int b = bh >> 4;
  const int d0 = jp * 2;

  const float* v0 = vT + (size_t)(h * DHn + d0) * NTOT + b * Tsz;
  const float* v1 = v0 + NTOT;

  for (int t = tid; t < 4096; t += 256)
    bufA[t] = make_float2(v0[t], v1[t]);

  fft4096(bufA, bufB, tid, -1.0f);

  const float* a = attn + (size_t)bh * Fn;
  for (int f = tid; f < 4096; f += 256) {
    int fm = (f <= 2048) ? f : (4096 - f);
    float s = a[fm];
    float2 z = bufA[f];
    bufA[f] = make_float2(z.x * s, z.y * s);
  }

  fft4096(bufA, bufB, tid, +1.0f);

  float* y0 = vbarT + (size_t)(h * DHn + d0) * NTOT + b * Tsz;
  float* y1 = y0 + NTOT;
  const float inv = 1.0f / 4096.0f;
  for (int t = tid; t < 4096; t += 256) {
    float2 z = bufA[t];
    y0[t] = z.x * inv;
    y1[t] = z.y * inv;
  }
}

__global__ void zero_kernel(float* __restrict__ p, int n) {
  int i = blockIdx.x * blockDim.x + threadIdx.x;
  if (i < n) p[i] = 0.f;
}

// ---------------------------------------------------------------------------
// Workspace layout (peak 185,598,464 B <= 202.9 MB proven by round 1):
//   [0,           67108864)   q rows of qkT; later vT [1024][16384] f32
//                             (written per-half after that half's qk_cross);
//                             finally VThi/VTlo [16384][1024] bf16.
//   [67108864,   134217728)   k rows of qkT; later vbarT [1024][16384] f32.
//   [134217728,  134742272)   attn_raw [64][2049] f32
//   [134742272,  135266816)   attn     [64][2049] f32
//   [135266816,  141558272)   Whi [3072][1024] bf16
//   [141558272,  147849728)   Wlo
//   [147849728,  164626944)   Xhi half [8192][1024] bf16 (2 halves, reused)
//   [164626944,  181404160)   Xlo half
//   [181404160,  183501312)   Wouthi [1024][1024] bf16
//   [183501312,  185598464)   Woutlo
// Hazard order per half: qk-GEMM (cols of half) -> qk_cross(half) ->
// v-GEMM writes vT cols of half (over dead q cols of that half only).
// ---------------------------------------------------------------------------
extern "C" void kernel_launch(void* const* d_in, const int* in_sizes, int n_in,
                              void* d_out, int out_size, void* d_ws, size_t ws_size,
                              hipStream_t stream) {
  const float* x    = (const float*)d_in[0];   // [4,4096,1024]
  const float* Wqkv = (const float*)d_in[1];   // [3072,1024]
  const float* Wout = (const float*)d_in[2];   // [1024,1024]
  const float* bout = (const float*)d_in[3];   // [1024]
  float* out = (float*)d_out;                  // [16384,1024]

  char* ws = (char*)d_ws;
  float* qkT      = (float*)ws;
  float* vT       = (float*)ws;
  __bf16* VThi    = (__bf16*)ws;
  __bf16* VTlo    = (__bf16*)(ws + 33554432ull);
  float* vbarT    = (float*)(ws + 67108864ull);
  float* attn_raw = (float*)(ws + 134217728ull);
  float* attn     = (float*)(ws + 134742272ull);
  __bf16* Whi     = (__bf16*)(ws + 135266816ull);
  __bf16* Wlo     = (__bf16*)(ws + 141558272ull);
  __bf16* Xhi     = (__bf16*)(ws + 147849728ull);
  __bf16* Xlo     = (__bf16*)(ws + 164626944ull);
  __bf16* Wouthi  = (__bf16*)(ws + 181404160ull);
  __bf16* Woutlo  = (__bf16*)(ws + 183501312ull);

  const int nraw = BHn * Fn;
  zero_kernel<<<(nraw + 255) / 256, 256, 0, stream>>>(attn_raw, nraw);

  // Weights -> hi/lo
  cvt_hilo_kernel<<<3072, 256, 0, stream>>>((const float4*)Wqkv,
                                            (bf16x4*)Whi, (bf16x4*)Wlo, 786432);
  cvt_hilo_kernel<<<1024, 256, 0, stream>>>((const float4*)Wout,
                                            (bf16x4*)Wouthi, (bf16x4*)Woutlo, 262144);

  // Per 2-batch half: convert X, q/k GEMM, qk cross-spectrum, v GEMM
  for (int half = 0; half < 2; ++half) {
    cvt_hilo_kernel<<<8192, 256, 0, stream>>>(
        (const float4*)(x + (size_t)half * HALFN * Csz),
        (bf16x4*)Xhi, (bf16x4*)Xlo, 2097152);
    // q,k rows: M=2048 (BM=256 -> gy=8), N=8192 (gx=32) -> 256 blocks
    gemm_8p<8><<<dim3(32, 8), 512, 0, stream>>>(Whi, Wlo, Xhi, Xlo,
                                                qkT, NTOT, half * HALFN, nullptr, 1);
    qk_cross_kernel<<<2048, 256, 0, stream>>>(qkT, attn_raw, half * 32);
    // v rows: M=1024 (BM=128 -> gy=8), N=8192 -> 256 blocks.
    // Writes vT cols of this half (dead q cols after qk_cross above).
    gemm_8p<4><<<dim3(32, 8), 512, 0, stream>>>(Whi + 2048 * Csz, Wlo + 2048 * Csz,
                                                Xhi, Xlo, vT, NTOT, half * HALFN,
                                                nullptr, 1);
  }

  softmax_kernel<<<BHn, 256, 0, stream>>>(attn_raw, attn);

  // spectral filter v -> vbar (k-region; k dead)
  v_filter_kernel<<<2048, 256, 0, stream>>>(vT, vbarT, attn);

  // vbarT [c][n] f32 -> VT hi/lo [n][c] bf16 (vT region dead)
  transpose_cvt_kernel<<<dim3(NTOT / 64, Csz / 64), 256, 0, stream>>>(vbarT, VThi, VTlo);

  // out = VT x Wout^T + bias: M=16384 (gy=64), N=1024 (gx=4) -> 256 blocks
  gemm_8p<8><<<dim3(4, 64), 512, 0, stream>>>(VThi, VTlo, Wouthi, Woutlo,
                                              out, Csz, 0, bout, 0);
}

// Round 7
// 653.098 us; speedup vs baseline: 2.7492x; 1.0694x over previous
//
#include <hip/hip_runtime.h>
#include <math.h>

// Problem constants
#define Bsz   4
#define Tsz   4096
#define Csz   1024
#define Hn    16
#define DHn   64
#define NTOT  (Bsz * Tsz)      // 16384 rows of x
#define M3    (3 * Csz)        // 3072
#define Fn    2049             // T/2 + 1
#define BHn   (Bsz * Hn)       // 64
#define HALFN 8192             // 2 batches of columns

typedef __bf16 bf16x8 __attribute__((ext_vector_type(8)));
typedef __bf16 bf16x4 __attribute__((ext_vector_type(4)));
typedef float  f32x4  __attribute__((ext_vector_type(4)));

// ---------------------------------------------------------------------------
// async global->LDS, 16B per lane. gptr per-lane; lptr wave-uniform
// (HW writes lptr + lane*16).
// ---------------------------------------------------------------------------
__device__ __forceinline__ void gload_lds16(const void* g, void* l) {
  __builtin_amdgcn_global_load_lds(
      (const __attribute__((address_space(1))) void*)g,
      (__attribute__((address_space(3))) void*)l, 16, 0, 0);
}

// ---------------------------------------------------------------------------
// f32 -> (hi, lo) bf16 split, 4 elems/thread. hi = RNE(v), lo = RNE(v - hi).
// ---------------------------------------------------------------------------
__global__ __launch_bounds__(256)
void cvt_hilo_kernel(const float4* __restrict__ in, bf16x4* __restrict__ hi,
                     bf16x4* __restrict__ lo, int n4) {
  int i = blockIdx.x * blockDim.x + threadIdx.x;
  if (i >= n4) return;
  float4 v = in[i];
  bf16x4 h, l;
  h[0] = (__bf16)v.x; h[1] = (__bf16)v.y; h[2] = (__bf16)v.z; h[3] = (__bf16)v.w;
  l[0] = (__bf16)(v.x - (float)h[0]);
  l[1] = (__bf16)(v.y - (float)h[1]);
  l[2] = (__bf16)(v.z - (float)h[2]);
  l[3] = (__bf16)(v.w - (float)h[3]);
  hi[i] = h;
  lo[i] = l;
}

// ---------------------------------------------------------------------------
// Transpose + hi/lo convert: src [1024][16384] f32 -> hi/lo [16384][1024] bf16.
// ---------------------------------------------------------------------------
__global__ __launch_bounds__(256)
void transpose_cvt_kernel(const float* __restrict__ src,
                          __bf16* __restrict__ hi, __bf16* __restrict__ lo) {
  __shared__ float tile[64][65];
  const int tid = threadIdx.x;
  const int n0 = blockIdx.x * 64;
  const int c0 = blockIdx.y * 64;
  const int col = tid & 63;
  const int row4 = tid >> 6;
#pragma unroll
  for (int i = 0; i < 16; ++i) {
    const int r = i * 4 + row4;
    tile[r][col] = src[(size_t)(c0 + r) * NTOT + n0 + col];
  }
  __syncthreads();
#pragma unroll
  for (int i = 0; i < 16; ++i) {
    const int n = i * 4 + row4;
    const float v = tile[col][n];
    const __bf16 h = (__bf16)v;
    const __bf16 l = (__bf16)(v - (float)h);
    hi[(size_t)(n0 + n) * Csz + c0 + col] = h;
    lo[(size_t)(n0 + n) * Csz + c0 + col] = l;
  }
}

// ===========================================================================
// gemm_8s: slot-ring counted-vmcnt split-bf16 MFMA GEMM (m201-style port).
//   C[m][nbase+n] = sum_k A[m][k]*B[n][k] (+bias[n] if bias), ldC row stride.
// 256x256 tile, 512 thr = 8 waves (2M x 4N), wave tile 128x64, BK=32, K=1024.
// LDS = ring of 8 slots x 16KB. Per K-tile t: slots 4t+{0:A0,1:B0,2:B1,3:A1}
// (A-half h = rowblocks {h*4..h*4+3, 8+h*4..}; B-half h = colblocks
// {wn*4+h*2+j}). Slot data: [8 chunks x 1KB hi][8 chunks x 1KB lo], chunk
// order == fragment ds_read order (lane-linear, conflict-free).
// Schedule per tile, 4 phases (mh,nh) = (0,0),(0,1),(1,0),(1,1):
//   vmcnt(8) counted (slots <=P+1 landed; 4 slots/8 loads stay in flight);
//   barrier; ds_read frags (A-half at mh-start; B halves at p0/p1, regs
//   persist whole tile); issue slot P+6 (2 gloads/wave); lgkmcnt(0);
//   sched_barrier; setprio(1); 24 MFMA; setprio(0).
// Prologue stages slots 0..5; tail drains 8->6->4->2->0. Hazard ledger:
// slot s overwrites s-8, whose last LDS read is >=2 phase-barriers earlier.
// ===========================================================================
template<int COLMAP>
__global__ __launch_bounds__(512, 2)
void gemm_8s(const __bf16* __restrict__ Ahi, const __bf16* __restrict__ Alo,
             const __bf16* __restrict__ Bhi, const __bf16* __restrict__ Blo,
             float* __restrict__ C, int ldC, int nbase,
             const float* __restrict__ bias) {
  __shared__ __align__(16) char lds[131072];

  const int tid  = threadIdx.x;
  const int wid  = tid >> 6;
  const int lane = tid & 63;
  const int wm = wid >> 2, wn = wid & 3;

  int bx = blockIdx.x, by = blockIdx.y;
  {
    const int gx = gridDim.x, gy = gridDim.y;
    const int nwg = gx * gy;
    if ((nwg & 7) == 0) {
      const int flat  = by * gx + bx;
      const int chunk = nwg >> 3;
      const int nf    = (flat & 7) * chunk + (flat >> 3);
      if (COLMAP) { bx = nf / gy; by = nf % gy; }
      else        { bx = nf % gx; by = nf / gx; }
    }
  }
  const int m0 = by * 256;
  const int n0 = bx * 256;

  const int r16 = lane & 15;
  const int kc  = lane >> 4;

  // staging roles (per wave): A rowblock rb = h*4 + (wid&3) + (wid&4 ? 8:0),
  // LDS chunk aq = (wid&3) + (wid&4 ? 4:0); B colblock cb = (wid&3)*4 + h*2
  // + (wid>>2), chunk bq = (wid&3)*2 + (wid>>2).
  const int aq = (wid & 3) + ((wid & 4) ? 4 : 0);
  const int bq = ((wid & 3) << 1) + (wid >> 2);
  const __bf16* gAh = Ahi + (size_t)(m0 + (wid & 3) * 16 + ((wid & 4) ? 128 : 0) + r16) * Csz + kc * 8;
  const __bf16* gAl = Alo + (size_t)(m0 + (wid & 3) * 16 + ((wid & 4) ? 128 : 0) + r16) * Csz + kc * 8;
  const __bf16* gBh = Bhi + (size_t)(n0 + (wid & 3) * 64 + (wid >> 2) * 16 + r16) * Csz + kc * 8;
  const __bf16* gBl = Blo + (size_t)(n0 + (wid & 3) * 64 + (wid >> 2) * 16 + r16) * Csz + kc * 8;

  auto stA = [&](int h, int ts, char* slot) {
    const size_t o = (size_t)h * 64 * Csz + ts * 32;
    gload_lds16(gAh + o, slot + aq * 1024);
    gload_lds16(gAl + o, slot + 8192 + aq * 1024);
  };
  auto stB = [&](int h, int ts, char* slot) {
    const size_t o = (size_t)h * 32 * Csz + ts * 32;
    gload_lds16(gBh + o, slot + bq * 1024);
    gload_lds16(gBl + o, slot + 8192 + bq * 1024);
  };

  f32x4 acc[8][4];
#pragma unroll
  for (int i = 0; i < 8; ++i)
#pragma unroll
    for (int j = 0; j < 4; ++j) acc[i][j] = (f32x4)(0.f);

  // prologue: slots 0..5 of the ring
  stA(0, 0, lds);            stB(0, 0, lds + 16384);
  stB(1, 0, lds + 32768);    stA(1, 0, lds + 49152);
  stA(0, 1, lds + 65536);    stB(0, 1, lds + 81920);

#pragma unroll 1
  for (int t = 0; t < 32; ++t) {
    char* cur = lds + ((t & 1) << 16);
    char* nxt = lds + (((t & 1) ^ 1) << 16);
    bf16x8 ah[4], al[4], bh[4], bl[4];

    // ---- phase 0: (mh0, nh0) -- reads A0 (8) + B0 (4); issues B1(t+1)
    if (t < 31) asm volatile("s_waitcnt vmcnt(8)" ::: "memory");
    else        asm volatile("s_waitcnt vmcnt(4)" ::: "memory");
    __builtin_amdgcn_s_barrier();
#pragma unroll
    for (int f = 0; f < 4; ++f) {
      const int off = (wm * 4 + f) * 1024 + lane * 16;
      ah[f] = *(const bf16x8*)(cur + off);
      al[f] = *(const bf16x8*)(cur + 8192 + off);
    }
#pragma unroll
    for (int j = 0; j < 2; ++j) {
      const int off = ((wn << 1) + j) * 1024 + lane * 16;
      bh[j] = *(const bf16x8*)(cur + 16384 + off);
      bl[j] = *(const bf16x8*)(cur + 16384 + 8192 + off);
    }
    if (t < 31) stB(1, t + 1, nxt + 32768);
    asm volatile("s_waitcnt lgkmcnt(0)" ::: "memory");
    __builtin_amdgcn_sched_barrier(0);
    __builtin_amdgcn_s_setprio(1);
#pragma unroll
    for (int f = 0; f < 4; ++f)
#pragma unroll
      for (int j = 0; j < 2; ++j) {
        f32x4 a_ = acc[f][j];
        a_ = __builtin_amdgcn_mfma_f32_16x16x32_bf16(ah[f], bh[j], a_, 0, 0, 0);
        a_ = __builtin_amdgcn_mfma_f32_16x16x32_bf16(ah[f], bl[j], a_, 0, 0, 0);
        a_ = __builtin_amdgcn_mfma_f32_16x16x32_bf16(al[f], bh[j], a_, 0, 0, 0);
        acc[f][j] = a_;
      }
    __builtin_amdgcn_s_setprio(0);

    // ---- phase 1: (mh0, nh1) -- reads B1 (4); issues A1(t+1)
    if (t < 31) asm volatile("s_waitcnt vmcnt(8)" ::: "memory");
    else        asm volatile("s_waitcnt vmcnt(2)" ::: "memory");
    __builtin_amdgcn_s_barrier();
#pragma unroll
    for (int j = 0; j < 2; ++j) {
      const int off = ((wn << 1) + j) * 1024 + lane * 16;
      bh[2 + j] = *(const bf16x8*)(cur + 32768 + off);
      bl[2 + j] = *(const bf16x8*)(cur + 32768 + 8192 + off);
    }
    if (t < 31) stA(1, t + 1, nxt + 49152);
    asm volatile("s_waitcnt lgkmcnt(0)" ::: "memory");
    __builtin_amdgcn_sched_barrier(0);
    __builtin_amdgcn_s_setprio(1);
#pragma unroll
    for (int f = 0; f < 4; ++f)
#pragma unroll
      for (int j = 0; j < 2; ++j) {
        f32x4 a_ = acc[f][2 + j];
        a_ = __builtin_amdgcn_mfma_f32_16x16x32_bf16(ah[f], bh[2 + j], a_, 0, 0, 0);
        a_ = __builtin_amdgcn_mfma_f32_16x16x32_bf16(ah[f], bl[2 + j], a_, 0, 0, 0);
        a_ = __builtin_amdgcn_mfma_f32_16x16x32_bf16(al[f], bh[2 + j], a_, 0, 0, 0);
        acc[f][2 + j] = a_;
      }
    __builtin_amdgcn_s_setprio(0);

    // ---- phase 2: (mh1, nh0) -- reads A1 (8); issues A0(t+2)
    if (t < 31) asm volatile("s_waitcnt vmcnt(8)" ::: "memory");
    else        asm volatile("s_waitcnt vmcnt(0)" ::: "memory");
    __builtin_amdgcn_s_barrier();
#pragma unroll
    for (int f = 0; f < 4; ++f) {
      const int off = (wm * 4 + f) * 1024 + lane * 16;
      ah[f] = *(const bf16x8*)(cur + 49152 + off);
      al[f] = *(const bf16x8*)(cur + 49152 + 8192 + off);
    }
    if (t < 30) stA(0, t + 2, cur);
    asm volatile("s_waitcnt lgkmcnt(0)" ::: "memory");
    __builtin_amdgcn_sched_barrier(0);
    __builtin_amdgcn_s_setprio(1);
#pragma unroll
    for (int f = 0; f < 4; ++f)
#pragma unroll
      for (int j = 0; j < 2; ++j) {
        f32x4 a_ = acc[4 + f][j];
        a_ = __builtin_amdgcn_mfma_f32_16x16x32_bf16(ah[f], bh[j], a_, 0, 0, 0);
        a_ = __builtin_amdgcn_mfma_f32_16x16x32_bf16(ah[f], bl[j], a_, 0, 0, 0);
        a_ = __builtin_amdgcn_mfma_f32_16x16x32_bf16(al[f], bh[j], a_, 0, 0, 0);
        acc[4 + f][j] = a_;
      }
    __builtin_amdgcn_s_setprio(0);

    // ---- phase 3: (mh1, nh1) -- no LDS reads; issues B0(t+2)
    __builtin_amdgcn_s_barrier();
    if (t < 30) stB(0, t + 2, cur + 16384);
    __builtin_amdgcn_s_setprio(1);
#pragma unroll
    for (int f = 0; f < 4; ++f)
#pragma unroll
      for (int j = 0; j < 2; ++j) {
        f32x4 a_ = acc[4 + f][2 + j];
        a_ = __builtin_amdgcn_mfma_f32_16x16x32_bf16(ah[f], bh[2 + j], a_, 0, 0, 0);
        a_ = __builtin_amdgcn_mfma_f32_16x16x32_bf16(ah[f], bl[2 + j], a_, 0, 0, 0);
        a_ = __builtin_amdgcn_mfma_f32_16x16x32_bf16(al[f], bh[2 + j], a_, 0, 0, 0);
        acc[4 + f][2 + j] = a_;
      }
    __builtin_amdgcn_s_setprio(0);
  }

  // epilogue: D row=(lane>>4)*4+r, col=lane&15 (m89 layout)
  const int cm = m0 + wm * 128 + (lane >> 4) * 4;
  const int cn = nbase + n0 + wn * 64 + (lane & 15);
  float bb[4];
#pragma unroll
  for (int g = 0; g < 4; ++g) bb[g] = bias ? bias[cn - nbase + g * 16] : 0.f;
#pragma unroll
  for (int fm = 0; fm < 8; ++fm)
#pragma unroll
    for (int r = 0; r < 4; ++r) {
      float* cp = C + (size_t)(cm + fm * 16 + r) * ldC + cn;
#pragma unroll
      for (int g = 0; g < 4; ++g) cp[g * 16] = acc[fm][g][r] + bb[g];
    }
}

// ---------------------------------------------------------------------------
// gemm_8p: round-6 2-buffer schedule, kept for the v-GEMM (MF=4, BM=128).
// ---------------------------------------------------------------------------
template<int MF>
__global__ __launch_bounds__(512, 2)
void gemm_8p(const __bf16* __restrict__ Ahi, const __bf16* __restrict__ Alo,
             const __bf16* __restrict__ Bhi, const __bf16* __restrict__ Blo,
             float* __restrict__ C, int ldC, int nbase,
             const float* __restrict__ bias, int colmap) {
  constexpr int BM  = 32 * MF;
  constexpr int SA  = BM * 64;
  constexpr int SB  = 16384;
  constexpr int BUF = 2 * SA + 2 * SB;
  __shared__ __align__(16) char lds[2 * BUF];

  const int tid  = threadIdx.x;
  const int wid  = tid >> 6;
  const int lane = tid & 63;
  const int wm = wid >> 2, wn = wid & 3;

  int bx = blockIdx.x, by = blockIdx.y;
  {
    const int gx = gridDim.x, gy = gridDim.y;
    const int nwg = gx * gy;
    if ((nwg & 7) == 0) {
      const int flat  = by * gx + bx;
      const int chunk = nwg >> 3;
      const int nf    = (flat & 7) * chunk + (flat >> 3);
      if (colmap) { bx = nf / gy; by = nf % gy; }
      else        { bx = nf % gx; by = nf / gx; }
    }
  }
  const int m0 = by * BM;
  const int n0 = bx * 256;

  const int r16 = lane & 15;
  const int kc  = lane >> 4;

  const __bf16* gAh0 = Ahi + (size_t)(m0 + wid * 16 + r16) * Csz + kc * 8;
  const __bf16* gAl0 = Alo + (size_t)(m0 + wid * 16 + r16) * Csz + kc * 8;
  const __bf16* gBh0 = Bhi + (size_t)(n0 + wid * 16 + r16) * Csz + kc * 8;
  const __bf16* gBl0 = Blo + (size_t)(n0 + wid * 16 + r16) * Csz + kc * 8;
  const __bf16* gBh1 = gBh0 + (size_t)128 * Csz;
  const __bf16* gBl1 = gBl0 + (size_t)128 * Csz;
  const int dW = wid * 1024;

  f32x4 acc[MF][4];
#pragma unroll
  for (int i = 0; i < MF; ++i)
#pragma unroll
    for (int j = 0; j < 4; ++j) acc[i][j] = (f32x4)(0.f);

  auto stage = [&](char* base, int k0) {
    gload_lds16(gAh0 + k0, base + dW);
    gload_lds16(gAl0 + k0, base + SA + dW);
    gload_lds16(gBh0 + k0, base + 2 * SA + dW);
    gload_lds16(gBh1 + k0, base + 2 * SA + dW + 8192);
    gload_lds16(gBl0 + k0, base + 2 * SA + SB + dW);
    gload_lds16(gBl1 + k0, base + 2 * SA + SB + dW + 8192);
  };

  stage(lds, 0);

  for (int t = 0; t < 32; ++t) {
    char* buf = lds + (t & 1) * BUF;
    asm volatile("s_waitcnt vmcnt(0)" ::: "memory");
    __builtin_amdgcn_s_barrier();
    if (t < 31) stage(lds + ((t & 1) ^ 1) * BUF, (t + 1) * 32);

#pragma unroll
    for (int mh = 0; mh < 2; ++mh) {
      bf16x8 ah[MF / 2], al[MF / 2];
#pragma unroll
      for (int f = 0; f < MF / 2; ++f) {
        const int off = (wm * MF + mh * (MF / 2) + f) * 1024 + lane * 16;
        ah[f] = *(const bf16x8*)(buf + off);
        al[f] = *(const bf16x8*)(buf + SA + off);
      }
#pragma unroll
      for (int nh = 0; nh < 2; ++nh) {
        bf16x8 bh[2], bl[2];
#pragma unroll
        for (int g = 0; g < 2; ++g) {
          const int off = (wn * 4 + nh * 2 + g) * 1024 + lane * 16;
          bh[g] = *(const bf16x8*)(buf + 2 * SA + off);
          bl[g] = *(const bf16x8*)(buf + 2 * SA + SB + off);
        }
        asm volatile("s_waitcnt lgkmcnt(0)" ::: "memory");
        __builtin_amdgcn_sched_barrier(0);
        __builtin_amdgcn_s_setprio(1);
#pragma unroll
        for (int f = 0; f < MF / 2; ++f)
#pragma unroll
          for (int g = 0; g < 2; ++g) {
            f32x4 a_ = acc[mh * (MF / 2) + f][nh * 2 + g];
            a_ = __builtin_amdgcn_mfma_f32_16x16x32_bf16(ah[f], bh[g], a_, 0, 0, 0);
            a_ = __builtin_amdgcn_mfma_f32_16x16x32_bf16(ah[f], bl[g], a_, 0, 0, 0);
            a_ = __builtin_amdgcn_mfma_f32_16x16x32_bf16(al[f], bh[g], a_, 0, 0, 0);
            acc[mh * (MF / 2) + f][nh * 2 + g] = a_;
          }
        __builtin_amdgcn_s_setprio(0);
        __builtin_amdgcn_s_barrier();
      }
    }
  }

  const int cm = m0 + wm * (MF * 16) + (lane >> 4) * 4;
  const int cn = nbase + n0 + wn * 64 + (lane & 15);
  float bb[4];
#pragma unroll
  for (int g = 0; g < 4; ++g) bb[g] = bias ? bias[cn - nbase + g * 16] : 0.f;
#pragma unroll
  for (int fm = 0; fm < MF; ++fm)
#pragma unroll
    for (int r = 0; r < 4; ++r) {
      float* cp = C + (size_t)(cm + fm * 16 + r) * ldC + cn;
#pragma unroll
      for (int g = 0; g < 4; ++g) cp[g * 16] = acc[fm][g][r] + bb[g];
    }
}

// ---------------------------------------------------------------------------
// 4096-point complex Stockham FFT in LDS (radix-2, 12 stages, autosort).
// ---------------------------------------------------------------------------
__device__ __forceinline__ void fft4096(float2* X, float2* Y, int tid, float sign) {
  float2* src = X;
  float2* dst = Y;
#pragma unroll 1
  for (int stage = 0; stage < 12; ++stage) {
    const int s = 1 << stage;
    __syncthreads();
#pragma unroll
    for (int it = 0; it < 8; ++it) {
      const int idx = tid + (it << 8);
      const int sp = idx & ~(s - 1);
      float2 a = src[idx];
      float2 b = src[idx + 2048];
      float ang = sign * (6.28318530717958647692f / 4096.0f) * (float)sp;
      float sn, cs;
      __sincosf(ang, &sn, &cs);
      float2 sum = make_float2(a.x + b.x, a.y + b.y);
      float2 dif = make_float2(a.x - b.x, a.y - b.y);
      float2 tw  = make_float2(dif.x * cs - dif.y * sn, dif.x * sn + dif.y * cs);
      const int o = idx + sp;
      dst[o] = sum;
      dst[o + s] = tw;
    }
    float2* t = src; src = dst; dst = t;
  }
  __syncthreads();
}

// ---------------------------------------------------------------------------
// qk_cross: z = q + i*k, FFT, Re(conj(Q)K) = 0.25*Im(conj(Zf+Zc)(Zf-Zc)).
// ---------------------------------------------------------------------------
__global__ __launch_bounds__(256)
void qk_cross_kernel(const float* __restrict__ qkT, float* __restrict__ attn_raw,
                     int bhbase) {
  __shared__ float2 bufA[4096];
  __shared__ float2 bufB[4096];
  const int tid = threadIdx.x;
  const int blk = blockIdx.x;
  const int d = blk & 63;
  const int bh = bhbase + (blk >> 6);
  const int h = bh & 15;
  const int b = bh >> 4;

  const float* qrow = qkT + (size_t)(h * DHn + d) * NTOT + b * Tsz;
  const float* krow = qkT + (size_t)(Csz + h * DHn + d) * NTOT + b * Tsz;

  for (int t = tid; t < 4096; t += 256)
    bufA[t] = make_float2(qrow[t], krow[t]);

  fft4096(bufA, bufB, tid, -1.0f);

  float* outp = attn_raw + (size_t)bh * Fn;
  for (int f = tid; f < Fn; f += 256) {
    float2 zf = bufA[f];
    float2 zn = bufA[(4096 - f) & 4095];
    float ar = zf.x + zn.x;
    float ai = zf.y - zn.y;
    float br = zf.x - zn.x;
    float bi = zf.y + zn.y;
    float val = 0.03125f * (ar * bi - ai * br);
    atomicAdd(&outp[f], val);
  }
}

// ---------------------------------------------------------------------------
__global__ __launch_bounds__(256)
void softmax_kernel(const float* __restrict__ raw, float* __restrict__ attn) {
  __shared__ float red[256];
  const int tid = threadIdx.x;
  const float* in = raw + (size_t)blockIdx.x * Fn;
  float* outp = attn + (size_t)blockIdx.x * Fn;

  float lmax = -3.4e38f;
  for (int f = tid; f < Fn; f += 256) lmax = fmaxf(lmax, in[f]);
  red[tid] = lmax;
  __syncthreads();
  for (int off = 128; off > 0; off >>= 1) {
    if (tid < off) red[tid] = fmaxf(red[tid], red[tid + off]);
    __syncthreads();
  }
  const float mx = red[0];
  __syncthreads();

  float lsum = 0.f;
  for (int f = tid; f < Fn; f += 256) lsum += __expf(in[f] - mx);
  red[tid] = lsum;
  __syncthreads();
  for (int off = 128; off > 0; off >>= 1) {
    if (tid < off) red[tid] += red[tid + off];
    __syncthreads();
  }
  const float inv = 1.0f / red[0];
  for (int f = tid; f < Fn; f += 256) outp[f] = __expf(in[f] - mx) * inv;
}

// ---------------------------------------------------------------------------
// v_filter: z = v[d0] + i*v[d1]; FFT; real symmetric filter; IFFT -> vbarT.
// ---------------------------------------------------------------------------
__global__ __launch_bounds__(256)
void v_filter_kernel(const float* __restrict__ vT, float* __restrict__ vbarT,
                     const float* __restrict__ attn) {
  __shared__ float2 bufA[4096];
  __shared__ float2 bufB[4096];
  const int tid = threadIdx.x;
  const int blk = blockIdx.x;
  const int jp = blk & 31;
  const int bh = blk >> 5;
  const int h = bh & 15;
  const int b = bh >> 4;
  const int d0 = jp * 2;

  const float* v0 = vT + (size_t)(h * DHn + d0) * NTOT + b * Tsz;
  const float* v1 = v0 + NTOT;

  for (int t = tid; t < 4096; t += 256)
    bufA[t] = make_float2(v0[t], v1[t]);

  fft4096(bufA, bufB, tid, -1.0f);

  const float* a = attn + (size_t)bh * Fn;
  for (int f = tid; f < 4096; f += 256) {
    int fm = (f <= 2048) ? f : (4096 - f);
    float s = a[fm];
    float2 z = bufA[f];
    bufA[f] = make_float2(z.x * s, z.y * s);
  }

  fft4096(bufA, bufB, tid, +1.0f);

  float* y0 = vbarT + (size_t)(h * DHn + d0) * NTOT + b * Tsz;
  float* y1 = y0 + NTOT;
  const float inv = 1.0f / 4096.0f;
  for (int t = tid; t < 4096; t += 256) {
    float2 z = bufA[t];
    y0[t] = z.x * inv;
    y1[t] = z.y * inv;
  }
}

__global__ void zero_kernel(float* __restrict__ p, int n) {
  int i = blockIdx.x * blockDim.x + threadIdx.x;
  if (i < n) p[i] = 0.f;
}

// ---------------------------------------------------------------------------
// Workspace layout (peak 185,598,464 B <= 202.9 MB proven by round 1):
//   [0,           67108864)   q rows of qkT; later vT; finally VThi/VTlo.
//   [67108864,   134217728)   k rows of qkT; later vbarT.
//   [134217728,  134742272)   attn_raw [64][2049] f32
//   [134742272,  135266816)   attn     [64][2049] f32
//   [135266816,  141558272)   Whi [3072][1024] bf16
//   [141558272,  147849728)   Wlo
//   [147849728,  164626944)   Xhi half [8192][1024] bf16 (2 halves, reused)
//   [164626944,  181404160)   Xlo half
//   [181404160,  183501312)   Wouthi [1024][1024] bf16
//   [183501312,  185598464)   Woutlo
// ---------------------------------------------------------------------------
extern "C" void kernel_launch(void* const* d_in, const int* in_sizes, int n_in,
                              void* d_out, int out_size, void* d_ws, size_t ws_size,
                              hipStream_t stream) {
  const float* x    = (const float*)d_in[0];   // [4,4096,1024]
  const float* Wqkv = (const float*)d_in[1];   // [3072,1024]
  const float* Wout = (const float*)d_in[2];   // [1024,1024]
  const float* bout = (const float*)d_in[3];   // [1024]
  float* out = (float*)d_out;                  // [16384,1024]

  char* ws = (char*)d_ws;
  float* qkT      = (float*)ws;
  float* vT       = (float*)ws;
  __bf16* VThi    = (__bf16*)ws;
  __bf16* VTlo    = (__bf16*)(ws + 33554432ull);
  float* vbarT    = (float*)(ws + 67108864ull);
  float* attn_raw = (float*)(ws + 134217728ull);
  float* attn     = (float*)(ws + 134742272ull);
  __bf16* Whi     = (__bf16*)(ws + 135266816ull);
  __bf16* Wlo     = (__bf16*)(ws + 141558272ull);
  __bf16* Xhi     = (__bf16*)(ws + 147849728ull);
  __bf16* Xlo     = (__bf16*)(ws + 164626944ull);
  __bf16* Wouthi  = (__bf16*)(ws + 181404160ull);
  __bf16* Woutlo  = (__bf16*)(ws + 183501312ull);

  const int nraw = BHn * Fn;
  zero_kernel<<<(nraw + 255) / 256, 256, 0, stream>>>(attn_raw, nraw);

  // Weights -> hi/lo
  cvt_hilo_kernel<<<3072, 256, 0, stream>>>((const float4*)Wqkv,
                                            (bf16x4*)Whi, (bf16x4*)Wlo, 786432);
  cvt_hilo_kernel<<<1024, 256, 0, stream>>>((const float4*)Wout,
                                            (bf16x4*)Wouthi, (bf16x4*)Woutlo, 262144);

  // Per 2-batch half: convert X, q/k GEMM (slot-ring), qk cross, v GEMM
  for (int half = 0; half < 2; ++half) {
    cvt_hilo_kernel<<<8192, 256, 0, stream>>>(
        (const float4*)(x + (size_t)half * HALFN * Csz),
        (bf16x4*)Xhi, (bf16x4*)Xlo, 2097152);
    gemm_8s<1><<<dim3(32, 8), 512, 0, stream>>>(Whi, Wlo, Xhi, Xlo,
                                                qkT, NTOT, half * HALFN, nullptr);
    qk_cross_kernel<<<2048, 256, 0, stream>>>(qkT, attn_raw, half * 32);
    gemm_8p<4><<<dim3(32, 8), 512, 0, stream>>>(Whi + 2048 * Csz, Wlo + 2048 * Csz,
                                                Xhi, Xlo, vT, NTOT, half * HALFN,
                                                nullptr, 1);
  }

  softmax_kernel<<<BHn, 256, 0, stream>>>(attn_raw, attn);

  v_filter_kernel<<<2048, 256, 0, stream>>>(vT, vbarT, attn);

  transpose_cvt_kernel<<<dim3(NTOT / 64, Csz / 64), 256, 0, stream>>>(vbarT, VThi, VTlo);

  gemm_8s<0><<<dim3(4, 64), 512, 0, stream>>>(VThi, VTlo, Wouthi, Woutlo,
                                              out, Csz, 0, bout);
}

// Round 8
// 587.227 us; speedup vs baseline: 3.0575x; 1.1122x over previous
//
#include <hip/hip_runtime.h>
#include <math.h>

// Problem constants
#define Bsz   4
#define Tsz   4096
#define Csz   1024
#define Hn    16
#define DHn   64
#define NTOT  (Bsz * Tsz)      // 16384 rows of x
#define M3    (3 * Csz)        // 3072
#define Fn    2049             // T/2 + 1
#define BHn   (Bsz * Hn)       // 64
#define HALFN 8192             // 2 batches of columns

typedef __bf16 bf16x8 __attribute__((ext_vector_type(8)));
typedef __bf16 bf16x4 __attribute__((ext_vector_type(4)));
typedef float  f32x4  __attribute__((ext_vector_type(4)));

// ---------------------------------------------------------------------------
// async global->LDS, 16B per lane. gptr per-lane; lptr wave-uniform
// (HW writes lptr + lane*16).
// ---------------------------------------------------------------------------
__device__ __forceinline__ void gload_lds16(const void* g, void* l) {
  __builtin_amdgcn_global_load_lds(
      (const __attribute__((address_space(1))) void*)g,
      (__attribute__((address_space(3))) void*)l, 16, 0, 0);
}

// ---------------------------------------------------------------------------
// f32 -> (hi, lo) bf16 split, 4 elems/thread. hi = RNE(v), lo = RNE(v - hi).
// ---------------------------------------------------------------------------
__global__ __launch_bounds__(256)
void cvt_hilo_kernel(const float4* __restrict__ in, bf16x4* __restrict__ hi,
                     bf16x4* __restrict__ lo, int n4) {
  int i = blockIdx.x * blockDim.x + threadIdx.x;
  if (i >= n4) return;
  float4 v = in[i];
  bf16x4 h, l;
  h[0] = (__bf16)v.x; h[1] = (__bf16)v.y; h[2] = (__bf16)v.z; h[3] = (__bf16)v.w;
  l[0] = (__bf16)(v.x - (float)h[0]);
  l[1] = (__bf16)(v.y - (float)h[1]);
  l[2] = (__bf16)(v.z - (float)h[2]);
  l[3] = (__bf16)(v.w - (float)h[3]);
  hi[i] = h;
  lo[i] = l;
}

// ---------------------------------------------------------------------------
// Transpose + hi/lo convert: src [1024][16384] f32 -> hi/lo [16384][1024] bf16.
// ---------------------------------------------------------------------------
__global__ __launch_bounds__(256)
void transpose_cvt_kernel(const float* __restrict__ src,
                          __bf16* __restrict__ hi, __bf16* __restrict__ lo) {
  __shared__ float tile[64][65];
  const int tid = threadIdx.x;
  const int n0 = blockIdx.x * 64;
  const int c0 = blockIdx.y * 64;
  const int col = tid & 63;
  const int row4 = tid >> 6;
#pragma unroll
  for (int i = 0; i < 16; ++i) {
    const int r = i * 4 + row4;
    tile[r][col] = src[(size_t)(c0 + r) * NTOT + n0 + col];
  }
  __syncthreads();
#pragma unroll
  for (int i = 0; i < 16; ++i) {
    const int n = i * 4 + row4;
    const float v = tile[col][n];
    const __bf16 h = (__bf16)v;
    const __bf16 l = (__bf16)(v - (float)h);
    hi[(size_t)(n0 + n) * Csz + c0 + col] = h;
    lo[(size_t)(n0 + n) * Csz + c0 + col] = l;
  }
}

// ===========================================================================
// gemm_8s: slot-ring counted-vmcnt split-bf16 MFMA GEMM (m201-style port).
// 256x256 tile, 512 thr = 8 waves (2M x 4N), BK=32, K=1024; 8x16KB LDS ring.
// See round-7 notes: counted vmcnt(8), per-phase barrier, setprio around MFMA.
// ===========================================================================
template<int COLMAP>
__global__ __launch_bounds__(512, 2)
void gemm_8s(const __bf16* __restrict__ Ahi, const __bf16* __restrict__ Alo,
             const __bf16* __restrict__ Bhi, const __bf16* __restrict__ Blo,
             float* __restrict__ C, int ldC, int nbase,
             const float* __restrict__ bias) {
  __shared__ __align__(16) char lds[131072];

  const int tid  = threadIdx.x;
  const int wid  = tid >> 6;
  const int lane = tid & 63;
  const int wm = wid >> 2, wn = wid & 3;

  int bx = blockIdx.x, by = blockIdx.y;
  {
    const int gx = gridDim.x, gy = gridDim.y;
    const int nwg = gx * gy;
    if ((nwg & 7) == 0) {
      const int flat  = by * gx + bx;
      const int chunk = nwg >> 3;
      const int nf    = (flat & 7) * chunk + (flat >> 3);
      if (COLMAP) { bx = nf / gy; by = nf % gy; }
      else        { bx = nf % gx; by = nf / gx; }
    }
  }
  const int m0 = by * 256;
  const int n0 = bx * 256;

  const int r16 = lane & 15;
  const int kc  = lane >> 4;

  const int aq = (wid & 3) + ((wid & 4) ? 4 : 0);
  const int bq = ((wid & 3) << 1) + (wid >> 2);
  const __bf16* gAh = Ahi + (size_t)(m0 + (wid & 3) * 16 + ((wid & 4) ? 128 : 0) + r16) * Csz + kc * 8;
  const __bf16* gAl = Alo + (size_t)(m0 + (wid & 3) * 16 + ((wid & 4) ? 128 : 0) + r16) * Csz + kc * 8;
  const __bf16* gBh = Bhi + (size_t)(n0 + (wid & 3) * 64 + (wid >> 2) * 16 + r16) * Csz + kc * 8;
  const __bf16* gBl = Blo + (size_t)(n0 + (wid & 3) * 64 + (wid >> 2) * 16 + r16) * Csz + kc * 8;

  auto stA = [&](int h, int ts, char* slot) {
    const size_t o = (size_t)h * 64 * Csz + ts * 32;
    gload_lds16(gAh + o, slot + aq * 1024);
    gload_lds16(gAl + o, slot + 8192 + aq * 1024);
  };
  auto stB = [&](int h, int ts, char* slot) {
    const size_t o = (size_t)h * 32 * Csz + ts * 32;
    gload_lds16(gBh + o, slot + bq * 1024);
    gload_lds16(gBl + o, slot + 8192 + bq * 1024);
  };

  f32x4 acc[8][4];
#pragma unroll
  for (int i = 0; i < 8; ++i)
#pragma unroll
    for (int j = 0; j < 4; ++j) acc[i][j] = (f32x4)(0.f);

  stA(0, 0, lds);            stB(0, 0, lds + 16384);
  stB(1, 0, lds + 32768);    stA(1, 0, lds + 49152);
  stA(0, 1, lds + 65536);    stB(0, 1, lds + 81920);

#pragma unroll 1
  for (int t = 0; t < 32; ++t) {
    char* cur = lds + ((t & 1) << 16);
    char* nxt = lds + (((t & 1) ^ 1) << 16);
    bf16x8 ah[4], al[4], bh[4], bl[4];

    // ---- phase 0
    if (t < 31) asm volatile("s_waitcnt vmcnt(8)" ::: "memory");
    else        asm volatile("s_waitcnt vmcnt(4)" ::: "memory");
    __builtin_amdgcn_s_barrier();
#pragma unroll
    for (int f = 0; f < 4; ++f) {
      const int off = (wm * 4 + f) * 1024 + lane * 16;
      ah[f] = *(const bf16x8*)(cur + off);
      al[f] = *(const bf16x8*)(cur + 8192 + off);
    }
#pragma unroll
    for (int j = 0; j < 2; ++j) {
      const int off = ((wn << 1) + j) * 1024 + lane * 16;
      bh[j] = *(const bf16x8*)(cur + 16384 + off);
      bl[j] = *(const bf16x8*)(cur + 16384 + 8192 + off);
    }
    if (t < 31) stB(1, t + 1, nxt + 32768);
    asm volatile("s_waitcnt lgkmcnt(0)" ::: "memory");
    __builtin_amdgcn_sched_barrier(0);
    __builtin_amdgcn_s_setprio(1);
#pragma unroll
    for (int f = 0; f < 4; ++f)
#pragma unroll
      for (int j = 0; j < 2; ++j) {
        f32x4 a_ = acc[f][j];
        a_ = __builtin_amdgcn_mfma_f32_16x16x32_bf16(ah[f], bh[j], a_, 0, 0, 0);
        a_ = __builtin_amdgcn_mfma_f32_16x16x32_bf16(ah[f], bl[j], a_, 0, 0, 0);
        a_ = __builtin_amdgcn_mfma_f32_16x16x32_bf16(al[f], bh[j], a_, 0, 0, 0);
        acc[f][j] = a_;
      }
    __builtin_amdgcn_s_setprio(0);

    // ---- phase 1
    if (t < 31) asm volatile("s_waitcnt vmcnt(8)" ::: "memory");
    else        asm volatile("s_waitcnt vmcnt(2)" ::: "memory");
    __builtin_amdgcn_s_barrier();
#pragma unroll
    for (int j = 0; j < 2; ++j) {
      const int off = ((wn << 1) + j) * 1024 + lane * 16;
      bh[2 + j] = *(const bf16x8*)(cur + 32768 + off);
      bl[2 + j] = *(const bf16x8*)(cur + 32768 + 8192 + off);
    }
    if (t < 31) stA(1, t + 1, nxt + 49152);
    asm volatile("s_waitcnt lgkmcnt(0)" ::: "memory");
    __builtin_amdgcn_sched_barrier(0);
    __builtin_amdgcn_s_setprio(1);
#pragma unroll
    for (int f = 0; f < 4; ++f)
#pragma unroll
      for (int j = 0; j < 2; ++j) {
        f32x4 a_ = acc[f][2 + j];
        a_ = __builtin_amdgcn_mfma_f32_16x16x32_bf16(ah[f], bh[2 + j], a_, 0, 0, 0);
        a_ = __builtin_amdgcn_mfma_f32_16x16x32_bf16(ah[f], bl[2 + j], a_, 0, 0, 0);
        a_ = __builtin_amdgcn_mfma_f32_16x16x32_bf16(al[f], bh[2 + j], a_, 0, 0, 0);
        acc[f][2 + j] = a_;
      }
    __builtin_amdgcn_s_setprio(0);

    // ---- phase 2
    if (t < 31) asm volatile("s_waitcnt vmcnt(8)" ::: "memory");
    else        asm volatile("s_waitcnt vmcnt(0)" ::: "memory");
    __builtin_amdgcn_s_barrier();
#pragma unroll
    for (int f = 0; f < 4; ++f) {
      const int off = (wm * 4 + f) * 1024 + lane * 16;
      ah[f] = *(const bf16x8*)(cur + 49152 + off);
      al[f] = *(const bf16x8*)(cur + 49152 + 8192 + off);
    }
    if (t < 30) stA(0, t + 2, cur);
    asm volatile("s_waitcnt lgkmcnt(0)" ::: "memory");
    __builtin_amdgcn_sched_barrier(0);
    __builtin_amdgcn_s_setprio(1);
#pragma unroll
    for (int f = 0; f < 4; ++f)
#pragma unroll
      for (int j = 0; j < 2; ++j) {
        f32x4 a_ = acc[4 + f][j];
        a_ = __builtin_amdgcn_mfma_f32_16x16x32_bf16(ah[f], bh[j], a_, 0, 0, 0);
        a_ = __builtin_amdgcn_mfma_f32_16x16x32_bf16(ah[f], bl[j], a_, 0, 0, 0);
        a_ = __builtin_amdgcn_mfma_f32_16x16x32_bf16(al[f], bh[j], a_, 0, 0, 0);
        acc[4 + f][j] = a_;
      }
    __builtin_amdgcn_s_setprio(0);

    // ---- phase 3
    __builtin_amdgcn_s_barrier();
    if (t < 30) stB(0, t + 2, cur + 16384);
    __builtin_amdgcn_s_setprio(1);
#pragma unroll
    for (int f = 0; f < 4; ++f)
#pragma unroll
      for (int j = 0; j < 2; ++j) {
        f32x4 a_ = acc[4 + f][2 + j];
        a_ = __builtin_amdgcn_mfma_f32_16x16x32_bf16(ah[f], bh[2 + j], a_, 0, 0, 0);
        a_ = __builtin_amdgcn_mfma_f32_16x16x32_bf16(ah[f], bl[2 + j], a_, 0, 0, 0);
        a_ = __builtin_amdgcn_mfma_f32_16x16x32_bf16(al[f], bh[2 + j], a_, 0, 0, 0);
        acc[4 + f][2 + j] = a_;
      }
    __builtin_amdgcn_s_setprio(0);
  }

  const int cm = m0 + wm * 128 + (lane >> 4) * 4;
  const int cn = nbase + n0 + wn * 64 + (lane & 15);
  float bb[4];
#pragma unroll
  for (int g = 0; g < 4; ++g) bb[g] = bias ? bias[cn - nbase + g * 16] : 0.f;
#pragma unroll
  for (int fm = 0; fm < 8; ++fm)
#pragma unroll
    for (int r = 0; r < 4; ++r) {
      float* cp = C + (size_t)(cm + fm * 16 + r) * ldC + cn;
#pragma unroll
      for (int g = 0; g < 4; ++g) cp[g * 16] = acc[fm][g][r] + bb[g];
    }
}

// ---------------------------------------------------------------------------
// gemm_8p: 2-buffer schedule, kept for the v-GEMM (MF=4, BM=128).
// ---------------------------------------------------------------------------
template<int MF>
__global__ __launch_bounds__(512, 2)
void gemm_8p(const __bf16* __restrict__ Ahi, const __bf16* __restrict__ Alo,
             const __bf16* __restrict__ Bhi, const __bf16* __restrict__ Blo,
             float* __restrict__ C, int ldC, int nbase,
             const float* __restrict__ bias, int colmap) {
  constexpr int BM  = 32 * MF;
  constexpr int SA  = BM * 64;
  constexpr int SB  = 16384;
  constexpr int BUF = 2 * SA + 2 * SB;
  __shared__ __align__(16) char lds[2 * BUF];

  const int tid  = threadIdx.x;
  const int wid  = tid >> 6;
  const int lane = tid & 63;
  const int wm = wid >> 2, wn = wid & 3;

  int bx = blockIdx.x, by = blockIdx.y;
  {
    const int gx = gridDim.x, gy = gridDim.y;
    const int nwg = gx * gy;
    if ((nwg & 7) == 0) {
      const int flat  = by * gx + bx;
      const int chunk = nwg >> 3;
      const int nf    = (flat & 7) * chunk + (flat >> 3);
      if (colmap) { bx = nf / gy; by = nf % gy; }
      else        { bx = nf % gx; by = nf / gx; }
    }
  }
  const int m0 = by * BM;
  const int n0 = bx * 256;

  const int r16 = lane & 15;
  const int kc  = lane >> 4;

  const __bf16* gAh0 = Ahi + (size_t)(m0 + wid * 16 + r16) * Csz + kc * 8;
  const __bf16* gAl0 = Alo + (size_t)(m0 + wid * 16 + r16) * Csz + kc * 8;
  const __bf16* gBh0 = Bhi + (size_t)(n0 + wid * 16 + r16) * Csz + kc * 8;
  const __bf16* gBl0 = Blo + (size_t)(n0 + wid * 16 + r16) * Csz + kc * 8;
  const __bf16* gBh1 = gBh0 + (size_t)128 * Csz;
  const __bf16* gBl1 = gBl0 + (size_t)128 * Csz;
  const int dW = wid * 1024;

  f32x4 acc[MF][4];
#pragma unroll
  for (int i = 0; i < MF; ++i)
#pragma unroll
    for (int j = 0; j < 4; ++j) acc[i][j] = (f32x4)(0.f);

  auto stage = [&](char* base, int k0) {
    gload_lds16(gAh0 + k0, base + dW);
    gload_lds16(gAl0 + k0, base + SA + dW);
    gload_lds16(gBh0 + k0, base + 2 * SA + dW);
    gload_lds16(gBh1 + k0, base + 2 * SA + dW + 8192);
    gload_lds16(gBl0 + k0, base + 2 * SA + SB + dW);
    gload_lds16(gBl1 + k0, base + 2 * SA + SB + dW + 8192);
  };

  stage(lds, 0);

  for (int t = 0; t < 32; ++t) {
    char* buf = lds + (t & 1) * BUF;
    asm volatile("s_waitcnt vmcnt(0)" ::: "memory");
    __builtin_amdgcn_s_barrier();
    if (t < 31) stage(lds + ((t & 1) ^ 1) * BUF, (t + 1) * 32);

#pragma unroll
    for (int mh = 0; mh < 2; ++mh) {
      bf16x8 ah[MF / 2], al[MF / 2];
#pragma unroll
      for (int f = 0; f < MF / 2; ++f) {
        const int off = (wm * MF + mh * (MF / 2) + f) * 1024 + lane * 16;
        ah[f] = *(const bf16x8*)(buf + off);
        al[f] = *(const bf16x8*)(buf + SA + off);
      }
#pragma unroll
      for (int nh = 0; nh < 2; ++nh) {
        bf16x8 bh[2], bl[2];
#pragma unroll
        for (int g = 0; g < 2; ++g) {
          const int off = (wn * 4 + nh * 2 + g) * 1024 + lane * 16;
          bh[g] = *(const bf16x8*)(buf + 2 * SA + off);
          bl[g] = *(const bf16x8*)(buf + 2 * SA + SB + off);
        }
        asm volatile("s_waitcnt lgkmcnt(0)" ::: "memory");
        __builtin_amdgcn_sched_barrier(0);
        __builtin_amdgcn_s_setprio(1);
#pragma unroll
        for (int f = 0; f < MF / 2; ++f)
#pragma unroll
          for (int g = 0; g < 2; ++g) {
            f32x4 a_ = acc[mh * (MF / 2) + f][nh * 2 + g];
            a_ = __builtin_amdgcn_mfma_f32_16x16x32_bf16(ah[f], bh[g], a_, 0, 0, 0);
            a_ = __builtin_amdgcn_mfma_f32_16x16x32_bf16(ah[f], bl[g], a_, 0, 0, 0);
            a_ = __builtin_amdgcn_mfma_f32_16x16x32_bf16(al[f], bh[g], a_, 0, 0, 0);
            acc[mh * (MF / 2) + f][nh * 2 + g] = a_;
          }
        __builtin_amdgcn_s_setprio(0);
        __builtin_amdgcn_s_barrier();
      }
    }
  }

  const int cm = m0 + wm * (MF * 16) + (lane >> 4) * 4;
  const int cn = nbase + n0 + wn * 64 + (lane & 15);
  float bb[4];
#pragma unroll
  for (int g = 0; g < 4; ++g) bb[g] = bias ? bias[cn - nbase + g * 16] : 0.f;
#pragma unroll
  for (int fm = 0; fm < MF; ++fm)
#pragma unroll
    for (int r = 0; r < 4; ++r) {
      float* cp = C + (size_t)(cm + fm * 16 + r) * ldC + cn;
#pragma unroll
      for (int g = 0; g < 4; ++g) cp[g * 16] = acc[fm][g][r] + bb[g];
    }
}

// ===========================================================================
// Radix-4 Stockham FFT, 4096 = 4^6, 6 stages, LDS twiddle table.
// tw[e] = (cos(2*pi*e/4096), sin(2*pi*e/4096)), e in [0,1024); sp < 1024
// always. Use w1 = (c, sign*s); w2 = w1^2; w3 = w1*w2. sign=-1 fwd, +1 inv
// (inverse unnormalized). Even #stages -> result lands back in X.
// Derivation verified against the (tested-correct) radix-2 convention:
//   dst[idx + 3*sp + j*s] = w^(j*sp) * y_j,  y = DFT4_sign(a0..a3).
// ===========================================================================
__device__ __forceinline__ void build_twiddle(float2* tw, int tid) {
  const float k = 6.28318530717958647692f / 4096.0f;
#pragma unroll
  for (int i = 0; i < 4; ++i) {
    const int e = tid + (i << 8);
    float sn, cs;
    __sincosf(k * (float)e, &sn, &cs);
    tw[e] = make_float2(cs, sn);
  }
}

__device__ __forceinline__ float2 cmul(float2 a, float2 b) {
  return make_float2(a.x * b.x - a.y * b.y, a.x * b.y + a.y * b.x);
}

__device__ __forceinline__ void fft4096_r4(float2* X, float2* Y,
                                           const float2* __restrict__ tw,
                                           int tid, float sign) {
  float2* src = X;
  float2* dst = Y;
#pragma unroll 1
  for (int stage = 0; stage < 6; ++stage) {
    const int s = 1 << (2 * stage);
    __syncthreads();
#pragma unroll
    for (int it = 0; it < 4; ++it) {
      const int idx = tid + (it << 8);          // < 1024
      const int sp = idx & ~(s - 1);
      float2 a0 = src[idx];
      float2 a1 = src[idx + 1024];
      float2 a2 = src[idx + 2048];
      float2 a3 = src[idx + 3072];
      float2 b0 = make_float2(a0.x + a2.x, a0.y + a2.y);
      float2 b1 = make_float2(a0.x - a2.x, a0.y - a2.y);
      float2 b2 = make_float2(a1.x + a3.x, a1.y + a3.y);
      float2 b3 = make_float2(a1.x - a3.x, a1.y - a3.y);
      float2 y0 = make_float2(b0.x + b2.x, b0.y + b2.y);
      float2 y2 = make_float2(b0.x - b2.x, b0.y - b2.y);
      float2 y1 = make_float2(b1.x - sign * b3.y, b1.y + sign * b3.x);
      float2 y3 = make_float2(b1.x + sign * b3.y, b1.y - sign * b3.x);
      float2 w1 = tw[sp];
      w1.y *= sign;
      float2 w2 = make_float2(w1.x * w1.x - w1.y * w1.y, 2.f * w1.x * w1.y);
      float2 w3 = cmul(w1, w2);
      const int o = idx + 3 * sp;
      dst[o]         = y0;
      dst[o + s]     = cmul(w1, y1);
      dst[o + 2 * s] = cmul(w2, y2);
      dst[o + 3 * s] = cmul(w3, y3);
    }
    float2* t = src; src = dst; dst = t;
  }
  __syncthreads();
}

// ---------------------------------------------------------------------------
// qk_cross: z = q + i*k, FFT, Re(conj(Q)K) = 0.25*Im(conj(Zf+Zc)(Zf-Zc)).
// ---------------------------------------------------------------------------
__global__ __launch_bounds__(256)
void qk_cross_kernel(const float* __restrict__ qkT, float* __restrict__ attn_raw,
                     int bhbase) {
  __shared__ float2 bufA[4096];
  __shared__ float2 bufB[4096];
  __shared__ float2 twid[1024];
  const int tid = threadIdx.x;
  const int blk = blockIdx.x;
  const int d = blk & 63;
  const int bh = bhbase + (blk >> 6);
  const int h = bh & 15;
  const int b = bh >> 4;

  build_twiddle(twid, tid);

  const float4* qrow = (const float4*)(qkT + (size_t)(h * DHn + d) * NTOT + b * Tsz);
  const float4* krow = (const float4*)(qkT + (size_t)(Csz + h * DHn + d) * NTOT + b * Tsz);
#pragma unroll
  for (int i = 0; i < 4; ++i) {
    const int t4 = tid + (i << 8);           // < 1024
    float4 qv = qrow[t4];
    float4 kv = krow[t4];
    bufA[t4 * 4 + 0] = make_float2(qv.x, kv.x);
    bufA[t4 * 4 + 1] = make_float2(qv.y, kv.y);
    bufA[t4 * 4 + 2] = make_float2(qv.z, kv.z);
    bufA[t4 * 4 + 3] = make_float2(qv.w, kv.w);
  }

  fft4096_r4(bufA, bufB, twid, tid, -1.0f);

  float* outp = attn_raw + (size_t)bh * Fn;
  for (int f = tid; f < Fn; f += 256) {
    float2 zf = bufA[f];
    float2 zn = bufA[(4096 - f) & 4095];
    float ar = zf.x + zn.x;
    float ai = zf.y - zn.y;
    float br = zf.x - zn.x;
    float bi = zf.y + zn.y;
    float val = 0.03125f * (ar * bi - ai * br);
    atomicAdd(&outp[f], val);
  }
}

// ---------------------------------------------------------------------------
__global__ __launch_bounds__(256)
void softmax_kernel(const float* __restrict__ raw, float* __restrict__ attn) {
  __shared__ float red[256];
  const int tid = threadIdx.x;
  const float* in = raw + (size_t)blockIdx.x * Fn;
  float* outp = attn + (size_t)blockIdx.x * Fn;

  float lmax = -3.4e38f;
  for (int f = tid; f < Fn; f += 256) lmax = fmaxf(lmax, in[f]);
  red[tid] = lmax;
  __syncthreads();
  for (int off = 128; off > 0; off >>= 1) {
    if (tid < off) red[tid] = fmaxf(red[tid], red[tid + off]);
    __syncthreads();
  }
  const float mx = red[0];
  __syncthreads();

  float lsum = 0.f;
  for (int f = tid; f < Fn; f += 256) lsum += __expf(in[f] - mx);
  red[tid] = lsum;
  __syncthreads();
  for (int off = 128; off > 0; off >>= 1) {
    if (tid < off) red[tid] += red[tid + off];
    __syncthreads();
  }
  const float inv = 1.0f / red[0];
  for (int f = tid; f < Fn; f += 256) outp[f] = __expf(in[f] - mx) * inv;
}

// ---------------------------------------------------------------------------
// v_filter: z = v[d0] + i*v[d1]; FFT; real symmetric filter; IFFT -> vbarT.
// ---------------------------------------------------------------------------
__global__ __launch_bounds__(256)
void v_filter_kernel(const float* __restrict__ vT, float* __restrict__ vbarT,
                     const float* __restrict__ attn) {
  __shared__ float2 bufA[4096];
  __shared__ float2 bufB[4096];
  __shared__ float2 twid[1024];
  const int tid = threadIdx.x;
  const int blk = blockIdx.x;
  const int jp = blk & 31;
  const int bh = blk >> 5;
  const int h = bh & 15;
  const int b = bh >> 4;
  const int d0 = jp * 2;

  build_twiddle(twid, tid);

  const float4* v0 = (const float4*)(vT + (size_t)(h * DHn + d0) * NTOT + b * Tsz);
  const float4* v1 = (const float4*)(vT + (size_t)(h * DHn + d0 + 1) * NTOT + b * Tsz);
#pragma unroll
  for (int i = 0; i < 4; ++i) {
    const int t4 = tid + (i << 8);
    float4 av = v0[t4];
    float4 bv = v1[t4];
    bufA[t4 * 4 + 0] = make_float2(av.x, bv.x);
    bufA[t4 * 4 + 1] = make_float2(av.y, bv.y);
    bufA[t4 * 4 + 2] = make_float2(av.z, bv.z);
    bufA[t4 * 4 + 3] = make_float2(av.w, bv.w);
  }

  fft4096_r4(bufA, bufB, twid, tid, -1.0f);

  const float* a = attn + (size_t)bh * Fn;
  for (int f = tid; f < 4096; f += 256) {
    int fm = (f <= 2048) ? f : (4096 - f);
    float s = a[fm];
    float2 z = bufA[f];
    bufA[f] = make_float2(z.x * s, z.y * s);
  }

  fft4096_r4(bufA, bufB, twid, tid, +1.0f);

  float* y0 = vbarT + (size_t)(h * DHn + d0) * NTOT + b * Tsz;
  float* y1 = y0 + NTOT;
  const float inv = 1.0f / 4096.0f;
  for (int t = tid; t < 4096; t += 256) {
    float2 z = bufA[t];
    y0[t] = z.x * inv;
    y1[t] = z.y * inv;
  }
}

__global__ void zero_kernel(float* __restrict__ p, int n) {
  int i = blockIdx.x * blockDim.x + threadIdx.x;
  if (i < n) p[i] = 0.f;
}

// ---------------------------------------------------------------------------
// Workspace layout (peak 185,598,464 B <= 202.9 MB proven by round 1):
//   [0,           67108864)   q rows of qkT; later vT; finally VThi/VTlo.
//   [67108864,   134217728)   k rows of qkT; later vbarT.
//   [134217728,  134742272)   attn_raw [64][2049] f32
//   [134742272,  135266816)   attn     [64][2049] f32
//   [135266816,  141558272)   Whi [3072][1024] bf16
//   [141558272,  147849728)   Wlo
//   [147849728,  164626944)   Xhi half [8192][1024] bf16 (2 halves, reused)
//   [164626944,  181404160)   Xlo half
//   [181404160,  183501312)   Wouthi [1024][1024] bf16
//   [183501312,  185598464)   Woutlo
// ---------------------------------------------------------------------------
extern "C" void kernel_launch(void* const* d_in, const int* in_sizes, int n_in,
                              void* d_out, int out_size, void* d_ws, size_t ws_size,
                              hipStream_t stream) {
  const float* x    = (const float*)d_in[0];   // [4,4096,1024]
  const float* Wqkv = (const float*)d_in[1];   // [3072,1024]
  const float* Wout = (const float*)d_in[2];   // [1024,1024]
  const float* bout = (const float*)d_in[3];   // [1024]
  float* out = (float*)d_out;                  // [16384,1024]

  char* ws = (char*)d_ws;
  float* qkT      = (float*)ws;
  float* vT       = (float*)ws;
  __bf16* VThi    = (__bf16*)ws;
  __bf16* VTlo    = (__bf16*)(ws + 33554432ull);
  float* vbarT    = (float*)(ws + 67108864ull);
  float* attn_raw = (float*)(ws + 134217728ull);
  float* attn     = (float*)(ws + 134742272ull);
  __bf16* Whi     = (__bf16*)(ws + 135266816ull);
  __bf16* Wlo     = (__bf16*)(ws + 141558272ull);
  __bf16* Xhi     = (__bf16*)(ws + 147849728ull);
  __bf16* Xlo     = (__bf16*)(ws + 164626944ull);
  __bf16* Wouthi  = (__bf16*)(ws + 181404160ull);
  __bf16* Woutlo  = (__bf16*)(ws + 183501312ull);

  const int nraw = BHn * Fn;
  zero_kernel<<<(nraw + 255) / 256, 256, 0, stream>>>(attn_raw, nraw);

  // Weights -> hi/lo
  cvt_hilo_kernel<<<3072, 256, 0, stream>>>((const float4*)Wqkv,
                                            (bf16x4*)Whi, (bf16x4*)Wlo, 786432);
  cvt_hilo_kernel<<<1024, 256, 0, stream>>>((const float4*)Wout,
                                            (bf16x4*)Wouthi, (bf16x4*)Woutlo, 262144);

  // Per 2-batch half: convert X, q/k GEMM (slot-ring), qk cross, v GEMM
  for (int half = 0; half < 2; ++half) {
    cvt_hilo_kernel<<<8192, 256, 0, stream>>>(
        (const float4*)(x + (size_t)half * HALFN * Csz),
        (bf16x4*)Xhi, (bf16x4*)Xlo, 2097152);
    gemm_8s<1><<<dim3(32, 8), 512, 0, stream>>>(Whi, Wlo, Xhi, Xlo,
                                                qkT, NTOT, half * HALFN, nullptr);
    qk_cross_kernel<<<2048, 256, 0, stream>>>(qkT, attn_raw, half * 32);
    gemm_8p<4><<<dim3(32, 8), 512, 0, stream>>>(Whi + 2048 * Csz, Wlo + 2048 * Csz,
                                                Xhi, Xlo, vT, NTOT, half * HALFN,
                                                nullptr, 1);
  }

  softmax_kernel<<<BHn, 256, 0, stream>>>(attn_raw, attn);

  v_filter_kernel<<<2048, 256, 0, stream>>>(vT, vbarT, attn);

  transpose_cvt_kernel<<<dim3(NTOT / 64, Csz / 64), 256, 0, stream>>>(vbarT, VThi, VTlo);

  gemm_8s<0><<<dim3(4, 64), 512, 0, stream>>>(VThi, VTlo, Wouthi, Woutlo,
                                              out, Csz, 0, bout);
}